// Round 1
// 207.386 us; speedup vs baseline: 1.0415x; 1.0415x over previous
//
#include <hip/hip_runtime.h>
#include <cstdint>
#include <cstddef>

typedef __bf16 bf16_t;
typedef bf16_t bf16x8 __attribute__((ext_vector_type(8)));
typedef bf16_t bf16x4 __attribute__((ext_vector_type(4)));
typedef float f32x4 __attribute__((ext_vector_type(4)));

__device__ __forceinline__ void gl_lds16(const void* g, void* l) {
  __builtin_amdgcn_global_load_lds(
      (const __attribute__((address_space(1))) void*)g,
      (__attribute__((address_space(3))) void*)l, 16, 0, 0);
}

__device__ __forceinline__ f32x4 mfma16(bf16x8 a, bf16x8 b, f32x4 c) {
  return __builtin_amdgcn_mfma_f32_16x16x32_bf16(a, b, c, 0, 0, 0);
}

// Scheduling fences: rule #18 — pin inline-asm waitcnts and raw barriers.
#define SCHED_FENCE() __builtin_amdgcn_sched_barrier(0)
#define WAIT_VM0()   do { asm volatile("s_waitcnt vmcnt(0)");   SCHED_FENCE(); } while (0)
#define WAIT_LGKM0() do { asm volatile("s_waitcnt lgkmcnt(0)"); SCHED_FENCE(); } while (0)
#define RAW_BAR()    do { __builtin_amdgcn_s_barrier();         SCHED_FENCE(); } while (0)

// ---------------- fp32 -> bf16 convert: 4 weights (1M elems) + 3 activations (4M) ---
// R1: activations pre-converted so gemm_proj can stage A via global_load_lds.
struct CvtArgs { const float* src[7]; bf16_t* dst[7]; };

__global__ __launch_bounds__(256) void convert_all(CvtArgs a) {
  unsigned g = blockIdx.x * 256u + threadIdx.x;   // 2,097,152 groups of 8
  unsigned seg, off;
  if (g < 524288u) {            // weights: 4 x 131072 groups
    seg = g >> 17; off = g & 131071u;
  } else {                      // activations: 3 x 524288 groups
    unsigned h = g - 524288u;
    seg = 4u + (h >> 19); off = h & 524287u;
  }
  const float4* s = (const float4*)a.src[seg] + (size_t)off * 2;
  float4 x0 = s[0], x1 = s[1];
  bf16x8 o;
  o[0] = (bf16_t)x0.x; o[1] = (bf16_t)x0.y; o[2] = (bf16_t)x0.z; o[3] = (bf16_t)x0.w;
  o[4] = (bf16_t)x1.x; o[5] = (bf16_t)x1.y; o[6] = (bf16_t)x1.z; o[7] = (bf16_t)x1.w;
  *(bf16x8*)(a.dst[seg] + (size_t)off * 8) = o;
}

// ---------------- staging helpers (pre-swizzled global source, linear LDS dest) ----
// 128 rows x 64 cols bf16, row stride 1024: 4 x gl_lds per thread.
__device__ __forceinline__ void stage128(const bf16_t* src, bf16_t* dst, int t, int w) {
  #pragma unroll
  for (int i = 0; i < 4; i++) {
    int g = t + i * 256;
    int r = g >> 3, pc = g & 7;
    int lc = pc ^ (r & 7);
    gl_lds16(src + (size_t)r * 1024 + lc * 8, dst + i * 2048 + w * 512);
  }
}
// 64 rows x 64 cols bf16, row stride 1024: 2 x gl_lds per thread.
__device__ __forceinline__ void stage64(const bf16_t* src, bf16_t* dst, int t, int w) {
  #pragma unroll
  for (int i = 0; i < 2; i++) {
    int g = t + i * 256;
    int r = g >> 3, pc = g & 7;
    int lc = pc ^ (r & 7);
    gl_lds16(src + (size_t)r * 1024 + lc * 8, dst + i * 2048 + w * 512);
  }
}

// ---------------- fused QKV projection (A bf16, W bf16, out bf16) ----------------
// R1: T3 minimum 2-phase pipeline — double-buffered LDS, stage(t+1) issued before
// compute(t), single vmcnt(0)+raw-barrier per K-step (no __syncthreads drain).
// z=0: V -> vt [bh][e][s_perm]; z=1: K -> [bh][s][e]; z=2: Q -> [bh][s][e]*0.125
struct ProjArgs {
  const bf16_t* A[3]; const bf16_t* W[3]; const float* bias[3];
  bf16_t* out[3]; float scale[3];
};

__global__ __launch_bounds__(256, 2) void gemm_proj(ProjArgs p) {
  __shared__ __attribute__((aligned(16))) unsigned char smem[65536];
  // buf layout: [a0 16K][b0 16K][a1 16K][b1 16K]
  const int z = blockIdx.z;
  const bf16_t* A = p.A[z] + (size_t)blockIdx.x * 128 * 1024;
  const bf16_t* W = p.W[z] + (size_t)blockIdx.y * 128 * 1024;

  const int t = threadIdx.x;
  const int w = t >> 6, l = t & 63;
  const int lq = l >> 4, lr = l & 15;
  const int mq = w & 1, nq = w >> 1;

  f32x4 acc[4][4];
  f32x4 zero = {0.f, 0.f, 0.f, 0.f};
  #pragma unroll
  for (int i = 0; i < 4; i++)
    #pragma unroll
    for (int j = 0; j < 4; j++) acc[i][j] = zero;

  // prologue: stage K-step 0 into buf0
  stage128(A, (bf16_t*)smem, t, w);
  stage128(W, (bf16_t*)(smem + 16384), t, w);
  WAIT_VM0();
  RAW_BAR();

  for (int step = 0; step < 16; ++step) {
    const int cur = step & 1;
    bf16_t* as = (bf16_t*)(smem + cur * 32768);
    bf16_t* bs = (bf16_t*)(smem + cur * 32768 + 16384);
    if (step < 15) {
      bf16_t* an = (bf16_t*)(smem + (cur ^ 1) * 32768);
      stage128(A + (step + 1) * 64, an, t, w);
      stage128(W + (step + 1) * 64, an + 8192, t, w);
    }
    SCHED_FENCE();   // all prefetch gl_lds issued before compute begins
    #pragma unroll
    for (int kk = 0; kk < 2; kk++) {
      bf16x8 af[4], bfr[4];
      #pragma unroll
      for (int i = 0; i < 4; i++) {
        int R = mq * 64 + i * 16 + lr;
        int ch = (kk * 4 + lq) ^ (R & 7);
        af[i] = *(const bf16x8*)(as + R * 64 + ch * 8);
      }
      #pragma unroll
      for (int j = 0; j < 4; j++) {
        int R = nq * 64 + j * 16 + lr;
        int ch = (kk * 4 + lq) ^ (R & 7);
        bfr[j] = *(const bf16x8*)(bs + R * 64 + ch * 8);
      }
      __builtin_amdgcn_s_setprio(1);
      #pragma unroll
      for (int i = 0; i < 4; i++)
        #pragma unroll
        for (int j = 0; j < 4; j++)
          acc[i][j] = mfma16(af[i], bfr[j], acc[i][j]);
      __builtin_amdgcn_s_setprio(0);
    }
    WAIT_VM0();      // stage(step+1) landed (counts only our 8 DMA loads)
    RAW_BAR();       // everyone done reading buf[cur] + everyone's stage done
  }

  const float* bias = p.bias[z];
  const float scale = p.scale[z];
  __syncthreads();
  bf16_t* ts = (bf16_t*)smem;  // 128 x 136 bf16 = 34,816 B
  #pragma unroll
  for (int i = 0; i < 4; i++) {
    #pragma unroll
    for (int j = 0; j < 4; j++) {
      int nl = nq * 64 + j * 16 + lr;
      float bz = bias[blockIdx.y * 128 + nl];
      #pragma unroll
      for (int r = 0; r < 4; r++) {
        int ml = mq * 64 + i * 16 + lq * 4 + r;
        bf16_t val = (bf16_t)((acc[i][j][r] + bz) * scale);
        if (z == 0) {
          int mlp = (ml & 96) | (((ml >> 2) & 3) << 3) | (((ml >> 4) & 1) << 2) | (ml & 3);
          ts[nl * 136 + mlp] = val;   // transposed (+permuted) for vt
        } else {
          ts[ml * 136 + nl] = val;
        }
      }
    }
  }
  __syncthreads();
  bf16_t* out = p.out[z];
  const int b = blockIdx.x >> 4, sbase = (blockIdx.x & 15) * 128;
  if (z == 0) {
    #pragma unroll
    for (int ii = 0; ii < 8; ii++) {
      int idx = t * 8 + ii * 2048;
      int rr = idx >> 7, cc = idx & 127;
      int n = blockIdx.y * 128 + rr;
      int h = n >> 6, e = n & 63;
      bf16x8 vq = *(const bf16x8*)(ts + rr * 136 + cc);
      *(bf16x8*)(out + ((size_t)(b * 16 + h) * 64 + e) * 2048 + sbase + cc) = vq;
    }
  } else {
    #pragma unroll
    for (int ii = 0; ii < 8; ii++) {
      int idx = t * 8 + ii * 2048;
      int rr = idx >> 7, cc = idx & 127;
      int n = blockIdx.y * 128 + cc;
      int h = n >> 6, e = n & 63;
      bf16x8 vq = *(const bf16x8*)(ts + rr * 136 + cc);
      *(bf16x8*)(out + ((size_t)(b * 16 + h) * 2048 + sbase + rr) * 64 + e) = vq;
    }
  }
}

// ---------------- flash attention, S^T formulation -----------------------------
// R1: K/V double-buffered with the same 2-phase prefetch pipeline. Q-staging and
// epilogue buffer alias buf1 (safe: Q secured in regs before kt=1 stage; epilogue
// after final barrier). LDS stays 32 KB -> 4 blocks/CU.
__global__ __launch_bounds__(256, 4) void attn(
    const bf16_t* __restrict__ qw, const bf16_t* __restrict__ kw,
    const bf16_t* __restrict__ vtw, bf16_t* __restrict__ att)
{
  __shared__ __attribute__((aligned(16))) unsigned char smem[32768];
  // [k0 8K][v0 8K][k1 8K][v1 8K]; qe aliases k1 (+1KB of v1 for epilogue)
  bf16_t* qe_s = (bf16_t*)(smem + 16384);
  const int bh = blockIdx.x, qt = blockIdx.y;
  const int t = threadIdx.x, w = t >> 6, l = t & 63, lq = l >> 4, lr = l & 15;

  const bf16_t* kb0 = kw + (size_t)bh * 131072;
  const bf16_t* vb0 = vtw + (size_t)bh * 131072;

  // prologue: Q tile -> qe region, K/V tile 0 -> buf0
  const bf16_t* qbase = qw + ((size_t)bh * 2048 + qt * 64) * 64;
  #pragma unroll
  for (int i = 0; i < 2; i++) {
    int g = t + i * 256;
    int r = g >> 3, pc = g & 7;
    int lc = pc ^ (r & 7);
    gl_lds16(qbase + (size_t)r * 64 + lc * 8, qe_s + i * 2048 + w * 512);
    gl_lds16(kb0 + (size_t)r * 64 + lc * 8, (bf16_t*)smem + i * 2048 + w * 512);
    gl_lds16(vb0 + (size_t)r * 2048 + lc * 8, (bf16_t*)(smem + 8192) + i * 2048 + w * 512);
  }
  WAIT_VM0();
  RAW_BAR();
  bf16x8 qf[2];
  #pragma unroll
  for (int kk = 0; kk < 2; kk++) {
    int R = w * 16 + lr;
    int ch = (kk * 4 + lq) ^ (R & 7);
    qf[kk] = *(const bf16x8*)(qe_s + R * 64 + ch * 8);
  }
  WAIT_LGKM0();   // Q secured in regs before buf1 (alias) is overwritten
  RAW_BAR();

  f32x4 O[4];
  f32x4 zero = {0.f, 0.f, 0.f, 0.f};
  #pragma unroll
  for (int et = 0; et < 4; et++) O[et] = zero;
  float lsum = 0.f;

  for (int kt = 0; kt < 32; ++kt) {
    const int cur = kt & 1;
    bf16_t* ks = (bf16_t*)(smem + cur * 16384);
    bf16_t* vs = (bf16_t*)(smem + cur * 16384 + 8192);
    if (kt < 31) {
      bf16_t* kn = (bf16_t*)(smem + (cur ^ 1) * 16384);
      const bf16_t* kbase = kb0 + (size_t)(kt + 1) * 64 * 64;
      const bf16_t* vbase = vb0 + (size_t)(kt + 1) * 64;
      #pragma unroll
      for (int i = 0; i < 2; i++) {
        int g = t + i * 256;
        int r = g >> 3, pc = g & 7;
        int lc = pc ^ (r & 7);
        gl_lds16(kbase + (size_t)r * 64 + lc * 8, kn + i * 2048 + w * 512);
        gl_lds16(vbase + (size_t)r * 2048 + lc * 8, kn + 4096 + i * 2048 + w * 512);
      }
    }
    SCHED_FENCE();

    f32x4 sc[4];
    #pragma unroll
    for (int j = 0; j < 4; j++) sc[j] = zero;
    #pragma unroll
    for (int kk = 0; kk < 2; kk++) {
      #pragma unroll
      for (int j = 0; j < 4; j++) {
        int R = j * 16 + lr;
        int ch = (kk * 4 + lq) ^ (R & 7);
        bf16x8 kf = *(const bf16x8*)(ks + R * 64 + ch * 8);
        __builtin_amdgcn_s_setprio(1);
        sc[j] = mfma16(kf, qf[kk], sc[j]);   // D[key][q]
        __builtin_amdgcn_s_setprio(0);
      }
    }

    bf16x8 pb[2];
    #pragma unroll
    for (int ks2 = 0; ks2 < 2; ks2++) {
      #pragma unroll
      for (int r = 0; r < 4; r++) {
        float e0 = __expf(sc[2 * ks2][r]);
        float e1 = __expf(sc[2 * ks2 + 1][r]);
        lsum += e0 + e1;
        pb[ks2][r] = (bf16_t)e0;
        pb[ks2][4 + r] = (bf16_t)e1;
      }
    }

    #pragma unroll
    for (int ks2 = 0; ks2 < 2; ks2++) {
      #pragma unroll
      for (int et = 0; et < 4; et++) {
        int R = et * 16 + lr;
        int ch = (ks2 * 4 + lq) ^ (R & 7);
        bf16x8 vf = *(const bf16x8*)(vs + R * 64 + ch * 8);
        __builtin_amdgcn_s_setprio(1);
        O[et] = mfma16(vf, pb[ks2], O[et]);
        __builtin_amdgcn_s_setprio(0);
      }
    }
    WAIT_VM0();   // next tile's DMA landed
    RAW_BAR();    // all waves done reading buf[cur]
  }

  float s = lsum;
  s += __shfl_xor(s, 16);
  s += __shfl_xor(s, 32);
  float rinv = 1.0f / s;

  #pragma unroll
  for (int et = 0; et < 4; et++) {
    bf16x4 pv;
    #pragma unroll
    for (int r = 0; r < 4; r++) pv[r] = (bf16_t)(O[et][r] * rinv);
    *(bf16x4*)(qe_s + (w * 16 + lr) * 72 + et * 16 + lq * 4) = pv;
  }
  __syncthreads();
  const int b = bh >> 4, h = bh & 15;
  #pragma unroll
  for (int i = 0; i < 2; i++) {
    int c = t + i * 256;
    int row = c >> 3, c8 = c & 7;
    bf16x8 vv = *(const bf16x8*)(qe_s + row * 72 + c8 * 8);
    *(bf16x8*)(att + ((size_t)b * 2048 + qt * 64 + row) * 1024 + h * 64 + c8 * 8) = vv;
  }
}

// ---------------- output projection (A bf16, W bf16, out fp32) ----------------
// R1: same 2-phase double-buffered pipeline. LDS 48 KB -> 3 blocks/CU.
__global__ __launch_bounds__(256, 3) void gemm_out(
    const bf16_t* __restrict__ A, const bf16_t* __restrict__ W,
    const float* __restrict__ bias, float* __restrict__ out)
{
  __shared__ __attribute__((aligned(16))) unsigned char smem[49152];
  // buf layout: [a0 8K][b0 16K][a1 8K][b1 16K]
  const bf16_t* Ab = A + (size_t)blockIdx.x * 64 * 1024;
  const bf16_t* Wb = W + (size_t)blockIdx.y * 128 * 1024;
  const int t = threadIdx.x, w = t >> 6, l = t & 63, lq = l >> 4, lr = l & 15;
  const int mh = w & 1, nh = w >> 1;

  f32x4 acc[2][4];
  f32x4 zero = {0.f, 0.f, 0.f, 0.f};
  #pragma unroll
  for (int i = 0; i < 2; i++)
    #pragma unroll
    for (int j = 0; j < 4; j++) acc[i][j] = zero;

  stage64(Ab, (bf16_t*)smem, t, w);
  stage128(Wb, (bf16_t*)(smem + 8192), t, w);
  WAIT_VM0();
  RAW_BAR();

  for (int step = 0; step < 16; ++step) {
    const int cur = step & 1;
    bf16_t* as = (bf16_t*)(smem + cur * 24576);
    bf16_t* bs = (bf16_t*)(smem + cur * 24576 + 8192);
    if (step < 15) {
      bf16_t* an = (bf16_t*)(smem + (cur ^ 1) * 24576);
      stage64(Ab + (step + 1) * 64, an, t, w);
      stage128(Wb + (step + 1) * 64, an + 4096, t, w);
    }
    SCHED_FENCE();
    #pragma unroll
    for (int kk = 0; kk < 2; kk++) {
      bf16x8 af[2], bfr[4];
      #pragma unroll
      for (int i = 0; i < 2; i++) {
        int R = mh * 32 + i * 16 + lr;
        int ch = (kk * 4 + lq) ^ (R & 7);
        af[i] = *(const bf16x8*)(as + R * 64 + ch * 8);
      }
      #pragma unroll
      for (int j = 0; j < 4; j++) {
        int R = nh * 64 + j * 16 + lr;
        int ch = (kk * 4 + lq) ^ (R & 7);
        bfr[j] = *(const bf16x8*)(bs + R * 64 + ch * 8);
      }
      __builtin_amdgcn_s_setprio(1);
      #pragma unroll
      for (int i = 0; i < 2; i++)
        #pragma unroll
        for (int j = 0; j < 4; j++)
          acc[i][j] = mfma16(af[i], bfr[j], acc[i][j]);
      __builtin_amdgcn_s_setprio(0);
    }
    WAIT_VM0();
    RAW_BAR();
  }

  #pragma unroll
  for (int i = 0; i < 2; i++) {
    #pragma unroll
    for (int j = 0; j < 4; j++) {
      int col = blockIdx.y * 128 + nh * 64 + j * 16 + lr;
      float bz = bias[col];
      #pragma unroll
      for (int r = 0; r < 4; r++) {
        int row = blockIdx.x * 64 + mh * 32 + i * 16 + lq * 4 + r;
        out[(size_t)row * 1024 + col] = acc[i][j][r] + bz;
      }
    }
  }
}

// ---------------- launch ----------------
extern "C" void kernel_launch(void* const* d_in, const int* in_sizes, int n_in,
                              void* d_out, int out_size, void* d_ws, size_t ws_size,
                              hipStream_t stream) {
  (void)in_sizes; (void)n_in; (void)out_size;
  const float* V  = (const float*)d_in[0];
  const float* Kx = (const float*)d_in[1];
  const float* Q  = (const float*)d_in[2];
  const float* Wv = (const float*)d_in[3];
  const float* bv = (const float*)d_in[4];
  const float* Wk = (const float*)d_in[5];
  const float* bk = (const float*)d_in[6];
  const float* Wq = (const float*)d_in[7];
  const float* bq = (const float*)d_in[8];
  const float* Wo = (const float*)d_in[9];
  const float* bo = (const float*)d_in[10];

  const size_t E = 1048576;
  if (ws_size < 20 * E * sizeof(bf16_t)) return;  // 40 MB needed

  bf16_t* ws = (bf16_t*)d_ws;
  bf16_t* cWo   = ws;            // 1E
  bf16_t* cWv   = ws + E;        // 1E
  bf16_t* cWk   = ws + 2 * E;    // 1E
  bf16_t* cWq   = ws + 3 * E;    // 1E
  bf16_t* q_ws  = ws + 4 * E;    // 4E  [bh][s][e], pre-scaled by 0.125
  bf16_t* k_ws  = ws + 8 * E;    // 4E  [bh][s][e]
  bf16_t* vt_ws = ws + 12 * E;   // 4E  [bh][e][s_perm]
  bf16_t* att_ws= ws + 16 * E;   // 4E  [b][s][h*64+e]

  // bf16 activation scratch: att_ws is dead until attn writes it; d_out is dead
  // until gemm_out writes it. All three consumed by gemm_proj before then.
  bf16_t* cV = att_ws;                         // 8 MB
  bf16_t* cK = (bf16_t*)d_out;                 // 8 MB (first half of out buffer)
  bf16_t* cQ = (bf16_t*)d_out + 4 * E;         // 8 MB (second half)

  CvtArgs ca;
  ca.src[0] = Wo; ca.src[1] = Wv; ca.src[2] = Wk; ca.src[3] = Wq;
  ca.src[4] = V;  ca.src[5] = Kx; ca.src[6] = Q;
  ca.dst[0] = cWo; ca.dst[1] = cWv; ca.dst[2] = cWk; ca.dst[3] = cWq;
  ca.dst[4] = cV;  ca.dst[5] = cK;  ca.dst[6] = cQ;
  convert_all<<<8192, 256, 0, stream>>>(ca);

  ProjArgs pa;
  pa.A[0] = cV;  pa.A[1] = cK;  pa.A[2] = cQ;
  pa.W[0] = cWv; pa.W[1] = cWk; pa.W[2] = cWq;
  pa.bias[0] = bv; pa.bias[1] = bk; pa.bias[2] = bq;
  pa.out[0] = vt_ws; pa.out[1] = k_ws; pa.out[2] = q_ws;
  pa.scale[0] = 1.f; pa.scale[1] = 1.f; pa.scale[2] = 0.125f;
  gemm_proj<<<dim3(32, 8, 3), 256, 0, stream>>>(pa);

  attn<<<dim3(32, 32), 256, 0, stream>>>(q_ws, k_ws, vt_ws, att_ws);

  gemm_out<<<dim3(64, 8), 256, 0, stream>>>(att_ws, cWo, bo, (float*)d_out);
}

// Round 2
// 205.447 us; speedup vs baseline: 1.0513x; 1.0094x over previous
//
#include <hip/hip_runtime.h>
#include <cstdint>
#include <cstddef>

typedef __bf16 bf16_t;
typedef bf16_t bf16x8 __attribute__((ext_vector_type(8)));
typedef bf16_t bf16x4 __attribute__((ext_vector_type(4)));
typedef float f32x4 __attribute__((ext_vector_type(4)));
typedef float f32x2 __attribute__((ext_vector_type(2)));

__device__ __forceinline__ void gl_lds16(const void* g, void* l) {
  __builtin_amdgcn_global_load_lds(
      (const __attribute__((address_space(1))) void*)g,
      (__attribute__((address_space(3))) void*)l, 16, 0, 0);
}

__device__ __forceinline__ f32x4 mfma16(bf16x8 a, bf16x8 b, f32x4 c) {
  return __builtin_amdgcn_mfma_f32_16x16x32_bf16(a, b, c, 0, 0, 0);
}

// 2^x in one TRANS op (log2e is pre-folded into the Q scale).
__device__ __forceinline__ float exp2_fast(float x) {
  float r;
  asm("v_exp_f32 %0, %1" : "=v"(r) : "v"(x));
  return r;
}

// Scheduling fences: rule #18 — pin inline-asm waitcnts and raw barriers.
#define SCHED_FENCE() __builtin_amdgcn_sched_barrier(0)
#define WAIT_VM0()   do { asm volatile("s_waitcnt vmcnt(0)");   SCHED_FENCE(); } while (0)
#define WAIT_LGKM0() do { asm volatile("s_waitcnt lgkmcnt(0)"); SCHED_FENCE(); } while (0)
#define RAW_BAR()    do { __builtin_amdgcn_s_barrier();         SCHED_FENCE(); } while (0)

// ---------------- fp32 -> bf16 convert: 4 weights (1M elems) + 3 activations (4M) ---
struct CvtArgs { const float* src[7]; bf16_t* dst[7]; };

__global__ __launch_bounds__(256) void convert_all(CvtArgs a) {
  unsigned g = blockIdx.x * 256u + threadIdx.x;   // 2,097,152 groups of 8
  unsigned seg, off;
  if (g < 524288u) {            // weights: 4 x 131072 groups
    seg = g >> 17; off = g & 131071u;
  } else {                      // activations: 3 x 524288 groups
    unsigned h = g - 524288u;
    seg = 4u + (h >> 19); off = h & 524287u;
  }
  const float4* s = (const float4*)a.src[seg] + (size_t)off * 2;
  float4 x0 = s[0], x1 = s[1];
  bf16x8 o;
  o[0] = (bf16_t)x0.x; o[1] = (bf16_t)x0.y; o[2] = (bf16_t)x0.z; o[3] = (bf16_t)x0.w;
  o[4] = (bf16_t)x1.x; o[5] = (bf16_t)x1.y; o[6] = (bf16_t)x1.z; o[7] = (bf16_t)x1.w;
  *(bf16x8*)(a.dst[seg] + (size_t)off * 8) = o;
}

// ---------------- staging helpers (pre-swizzled global source, linear LDS dest) ----
__device__ __forceinline__ void stage128(const bf16_t* src, bf16_t* dst, int t, int w) {
  #pragma unroll
  for (int i = 0; i < 4; i++) {
    int g = t + i * 256;
    int r = g >> 3, pc = g & 7;
    int lc = pc ^ (r & 7);
    gl_lds16(src + (size_t)r * 1024 + lc * 8, dst + i * 2048 + w * 512);
  }
}
__device__ __forceinline__ void stage64(const bf16_t* src, bf16_t* dst, int t, int w) {
  #pragma unroll
  for (int i = 0; i < 2; i++) {
    int g = t + i * 256;
    int r = g >> 3, pc = g & 7;
    int lc = pc ^ (r & 7);
    gl_lds16(src + (size_t)r * 1024 + lc * 8, dst + i * 2048 + w * 512);
  }
}

// ---------------- fused QKV projection (A bf16, W bf16, out bf16) ----------------
// z=0: V -> vt [bh][e][s_perm]; z=1: K -> [bh][s][e]; z=2: Q -> [bh][s][e]*qscale
struct ProjArgs {
  const bf16_t* A[3]; const bf16_t* W[3]; const float* bias[3];
  bf16_t* out[3]; float scale[3];
};

__global__ __launch_bounds__(256, 2) void gemm_proj(ProjArgs p) {
  __shared__ __attribute__((aligned(16))) unsigned char smem[65536];
  const int z = blockIdx.z;
  const bf16_t* A = p.A[z] + (size_t)blockIdx.x * 128 * 1024;
  const bf16_t* W = p.W[z] + (size_t)blockIdx.y * 128 * 1024;

  const int t = threadIdx.x;
  const int w = t >> 6, l = t & 63;
  const int lq = l >> 4, lr = l & 15;
  const int mq = w & 1, nq = w >> 1;

  f32x4 acc[4][4];
  f32x4 zero = {0.f, 0.f, 0.f, 0.f};
  #pragma unroll
  for (int i = 0; i < 4; i++)
    #pragma unroll
    for (int j = 0; j < 4; j++) acc[i][j] = zero;

  stage128(A, (bf16_t*)smem, t, w);
  stage128(W, (bf16_t*)(smem + 16384), t, w);
  WAIT_VM0();
  RAW_BAR();

  for (int step = 0; step < 16; ++step) {
    const int cur = step & 1;
    bf16_t* as = (bf16_t*)(smem + cur * 32768);
    bf16_t* bs = (bf16_t*)(smem + cur * 32768 + 16384);
    if (step < 15) {
      bf16_t* an = (bf16_t*)(smem + (cur ^ 1) * 32768);
      stage128(A + (step + 1) * 64, an, t, w);
      stage128(W + (step + 1) * 64, an + 8192, t, w);
    }
    SCHED_FENCE();
    #pragma unroll
    for (int kk = 0; kk < 2; kk++) {
      bf16x8 af[4], bfr[4];
      #pragma unroll
      for (int i = 0; i < 4; i++) {
        int R = mq * 64 + i * 16 + lr;
        int ch = (kk * 4 + lq) ^ (R & 7);
        af[i] = *(const bf16x8*)(as + R * 64 + ch * 8);
      }
      #pragma unroll
      for (int j = 0; j < 4; j++) {
        int R = nq * 64 + j * 16 + lr;
        int ch = (kk * 4 + lq) ^ (R & 7);
        bfr[j] = *(const bf16x8*)(bs + R * 64 + ch * 8);
      }
      __builtin_amdgcn_s_setprio(1);
      #pragma unroll
      for (int i = 0; i < 4; i++)
        #pragma unroll
        for (int j = 0; j < 4; j++)
          acc[i][j] = mfma16(af[i], bfr[j], acc[i][j]);
      __builtin_amdgcn_s_setprio(0);
    }
    WAIT_VM0();
    RAW_BAR();
  }

  const float* bias = p.bias[z];
  const float scale = p.scale[z];
  __syncthreads();
  bf16_t* ts = (bf16_t*)smem;  // 128 x 136 bf16 = 34,816 B
  #pragma unroll
  for (int i = 0; i < 4; i++) {
    #pragma unroll
    for (int j = 0; j < 4; j++) {
      int nl = nq * 64 + j * 16 + lr;
      float bz = bias[blockIdx.y * 128 + nl];
      #pragma unroll
      for (int r = 0; r < 4; r++) {
        int ml = mq * 64 + i * 16 + lq * 4 + r;
        bf16_t val = (bf16_t)((acc[i][j][r] + bz) * scale);
        if (z == 0) {
          int mlp = (ml & 96) | (((ml >> 2) & 3) << 3) | (((ml >> 4) & 1) << 2) | (ml & 3);
          ts[nl * 136 + mlp] = val;   // transposed (+permuted) for vt
        } else {
          ts[ml * 136 + nl] = val;
        }
      }
    }
  }
  __syncthreads();
  bf16_t* out = p.out[z];
  const int b = blockIdx.x >> 4, sbase = (blockIdx.x & 15) * 128;
  if (z == 0) {
    #pragma unroll
    for (int ii = 0; ii < 8; ii++) {
      int idx = t * 8 + ii * 2048;
      int rr = idx >> 7, cc = idx & 127;
      int n = blockIdx.y * 128 + rr;
      int h = n >> 6, e = n & 63;
      bf16x8 vq = *(const bf16x8*)(ts + rr * 136 + cc);
      *(bf16x8*)(out + ((size_t)(b * 16 + h) * 64 + e) * 2048 + sbase + cc) = vq;
    }
  } else {
    #pragma unroll
    for (int ii = 0; ii < 8; ii++) {
      int idx = t * 8 + ii * 2048;
      int rr = idx >> 7, cc = idx & 127;
      int n = blockIdx.y * 128 + cc;
      int h = n >> 6, e = n & 63;
      bf16x8 vq = *(const bf16x8*)(ts + rr * 136 + cc);
      *(bf16x8*)(out + ((size_t)(b * 16 + h) * 2048 + sbase + rr) * 64 + e) = vq;
    }
  }
}

// ---------------- flash attention, S^T formulation -----------------------------
// R2: T15 deferred-PV pipeline. Iteration kt issues QK(kt) and PV(kt-1) as two
// independent MFMA clusters; softmax(kt) VALU overlaps them. V-frags of tile kt
// are pulled to registers (single set, WAR-ordered after PV consumes them) and
// lgkm-drained before the barrier, so the deferred PV never reads a buffer that
// staging is overwriting. P ping-pongs through pbA/pbB via 2-unroll (no copies).
// Softmax uses bare v_exp_f32 (log2e folded into Q pre-scale) + packed f32x2 lsum.
__global__ __launch_bounds__(256, 4) void attn(
    const bf16_t* __restrict__ qw, const bf16_t* __restrict__ kw,
    const bf16_t* __restrict__ vtw, bf16_t* __restrict__ att)
{
  __shared__ __attribute__((aligned(16))) unsigned char smem[32768];
  // buf0 = [k:0..8K | v:8K..16K], buf1 = [16K..24K | 24K..32K]; qe aliases buf1
  bf16_t* qe_s = (bf16_t*)(smem + 16384);
  const int bh = blockIdx.x, qt = blockIdx.y;
  const int t = threadIdx.x, w = t >> 6, l = t & 63, lq = l >> 4, lr = l & 15;

  const bf16_t* kb0 = kw + (size_t)bh * 131072;
  const bf16_t* vb0 = vtw + (size_t)bh * 131072;

  // prologue: Q tile -> qe region (buf1), K/V tile 0 -> buf0
  const bf16_t* qbase = qw + ((size_t)bh * 2048 + qt * 64) * 64;
  #pragma unroll
  for (int i = 0; i < 2; i++) {
    int g = t + i * 256;
    int r = g >> 3, pc = g & 7;
    int lc = pc ^ (r & 7);
    gl_lds16(qbase + (size_t)r * 64 + lc * 8, qe_s + i * 2048 + w * 512);
    gl_lds16(kb0 + (size_t)r * 64 + lc * 8, (bf16_t*)smem + i * 2048 + w * 512);
    gl_lds16(vb0 + (size_t)r * 2048 + lc * 8, (bf16_t*)(smem + 8192) + i * 2048 + w * 512);
  }
  WAIT_VM0();
  RAW_BAR();
  bf16x8 qf[2];
  #pragma unroll
  for (int kk = 0; kk < 2; kk++) {
    int R = w * 16 + lr;
    int ch = (kk * 4 + lq) ^ (R & 7);
    qf[kk] = *(const bf16x8*)(qe_s + R * 64 + ch * 8);
  }
  WAIT_LGKM0();   // Q secured in regs before buf1 (alias) is overwritten
  RAW_BAR();

  f32x4 O[4];
  f32x4 zero = {0.f, 0.f, 0.f, 0.f};
  #pragma unroll
  for (int et = 0; et < 4; et++) O[et] = zero;
  f32x2 ls = {0.f, 0.f};
  bf16x8 vf[8];      // V-frags of current tile (consumed by NEXT iter's PV)
  bf16x8 pbA[2], pbB[2];

#define ATTN_BODY(KT, CUR, PBOUT, PBIN, FIRST, DOSTAGE)                          \
  {                                                                              \
    bf16_t* ksb = (bf16_t*)(smem + (CUR) * 16384);                               \
    bf16_t* vsb = (bf16_t*)(smem + (CUR) * 16384 + 8192);                        \
    if (DOSTAGE) {                                                               \
      bf16_t* kn = (bf16_t*)(smem + ((CUR) ^ 1) * 16384);                        \
      const bf16_t* kbase = kb0 + (size_t)((KT) + 1) * 4096;                     \
      const bf16_t* vbase = vb0 + (size_t)((KT) + 1) * 64;                       \
      _Pragma("unroll")                                                          \
      for (int i = 0; i < 2; i++) {                                              \
        int g = t + i * 256;                                                     \
        int r = g >> 3, pc = g & 7;                                              \
        int lc = pc ^ (r & 7);                                                   \
        gl_lds16(kbase + (size_t)r * 64 + lc * 8, kn + i * 2048 + w * 512);      \
        gl_lds16(vbase + (size_t)r * 2048 + lc * 8, kn + 4096 + i * 2048 + w * 512); \
      }                                                                          \
    }                                                                            \
    f32x4 sc[4];                                                                 \
    _Pragma("unroll")                                                            \
    for (int j = 0; j < 4; j++) sc[j] = zero;                                    \
    __builtin_amdgcn_s_setprio(1);                                               \
    if (!(FIRST)) {                                                              \
      _Pragma("unroll")                                                          \
      for (int ks2 = 0; ks2 < 2; ks2++)                                          \
        _Pragma("unroll")                                                        \
        for (int et = 0; et < 4; et++)                                           \
          O[et] = mfma16(vf[ks2 * 4 + et], (PBIN)[ks2], O[et]);                  \
    }                                                                            \
    _Pragma("unroll")                                                            \
    for (int kk = 0; kk < 2; kk++)                                               \
      _Pragma("unroll")                                                          \
      for (int j = 0; j < 4; j++) {                                              \
        int R = j * 16 + lr;                                                     \
        int ch = (kk * 4 + lq) ^ (R & 7);                                        \
        bf16x8 kf = *(const bf16x8*)(ksb + R * 64 + ch * 8);                     \
        sc[j] = mfma16(kf, qf[kk], sc[j]);                                       \
      }                                                                          \
    __builtin_amdgcn_s_setprio(0);                                               \
    _Pragma("unroll")                                                            \
    for (int ks2 = 0; ks2 < 2; ks2++)                                            \
      _Pragma("unroll")                                                          \
      for (int et = 0; et < 4; et++) {                                           \
        int R = et * 16 + lr;                                                    \
        int ch = (ks2 * 4 + lq) ^ (R & 7);                                       \
        vf[ks2 * 4 + et] = *(const bf16x8*)(vsb + R * 64 + ch * 8);              \
      }                                                                          \
    _Pragma("unroll")                                                            \
    for (int ks2 = 0; ks2 < 2; ks2++)                                            \
      _Pragma("unroll")                                                          \
      for (int r = 0; r < 4; r++) {                                              \
        float e0 = exp2_fast(sc[2 * ks2][r]);                                    \
        float e1 = exp2_fast(sc[2 * ks2 + 1][r]);                                \
        f32x2 ee = {e0, e1};                                                     \
        ls += ee;                                                                \
        (PBOUT)[ks2][r] = (bf16_t)e0;                                            \
        (PBOUT)[ks2][4 + r] = (bf16_t)e1;                                        \
      }                                                                          \
    WAIT_LGKM0();     /* vf + kf reads retired before buffer can be reused */    \
    if (DOSTAGE) WAIT_VM0(); /* stage(KT+1) landed */                            \
    RAW_BAR();                                                                   \
  }

  ATTN_BODY(0, 0, pbA, pbB, true, true);
  ATTN_BODY(1, 1, pbB, pbA, false, true);
  for (int kt2 = 1; kt2 < 16; ++kt2) {
    const int kt = kt2 * 2;
    ATTN_BODY(kt, 0, pbA, pbB, false, true);
    ATTN_BODY(kt + 1, 1, pbB, pbA, false, (kt2 < 15));
  }
#undef ATTN_BODY

  // epilogue PV: tile 31 (pbB + vf)
  #pragma unroll
  for (int ks2 = 0; ks2 < 2; ks2++)
    #pragma unroll
    for (int et = 0; et < 4; et++)
      O[et] = mfma16(vf[ks2 * 4 + et], pbB[ks2], O[et]);

  float s = ls[0] + ls[1];
  s += __shfl_xor(s, 16);
  s += __shfl_xor(s, 32);
  float rinv = 1.0f / s;

  #pragma unroll
  for (int et = 0; et < 4; et++) {
    bf16x4 pv;
    #pragma unroll
    for (int r = 0; r < 4; r++) pv[r] = (bf16_t)(O[et][r] * rinv);
    *(bf16x4*)(qe_s + (w * 16 + lr) * 72 + et * 16 + lq * 4) = pv;
  }
  __syncthreads();
  const int b = bh >> 4, h = bh & 15;
  #pragma unroll
  for (int i = 0; i < 2; i++) {
    int c = t + i * 256;
    int row = c >> 3, c8 = c & 7;
    bf16x8 vv = *(const bf16x8*)(qe_s + row * 72 + c8 * 8);
    *(bf16x8*)(att + ((size_t)b * 2048 + qt * 64 + row) * 1024 + h * 64 + c8 * 8) = vv;
  }
}

// ---------------- output projection (A bf16, W bf16, out fp32) ----------------
__global__ __launch_bounds__(256, 3) void gemm_out(
    const bf16_t* __restrict__ A, const bf16_t* __restrict__ W,
    const float* __restrict__ bias, float* __restrict__ out)
{
  __shared__ __attribute__((aligned(16))) unsigned char smem[49152];
  const bf16_t* Ab = A + (size_t)blockIdx.x * 64 * 1024;
  const bf16_t* Wb = W + (size_t)blockIdx.y * 128 * 1024;
  const int t = threadIdx.x, w = t >> 6, l = t & 63, lq = l >> 4, lr = l & 15;
  const int mh = w & 1, nh = w >> 1;

  f32x4 acc[2][4];
  f32x4 zero = {0.f, 0.f, 0.f, 0.f};
  #pragma unroll
  for (int i = 0; i < 2; i++)
    #pragma unroll
    for (int j = 0; j < 4; j++) acc[i][j] = zero;

  stage64(Ab, (bf16_t*)smem, t, w);
  stage128(Wb, (bf16_t*)(smem + 8192), t, w);
  WAIT_VM0();
  RAW_BAR();

  for (int step = 0; step < 16; ++step) {
    const int cur = step & 1;
    bf16_t* as = (bf16_t*)(smem + cur * 24576);
    bf16_t* bs = (bf16_t*)(smem + cur * 24576 + 8192);
    if (step < 15) {
      bf16_t* an = (bf16_t*)(smem + (cur ^ 1) * 24576);
      stage64(Ab + (step + 1) * 64, an, t, w);
      stage128(Wb + (step + 1) * 64, an + 4096, t, w);
    }
    SCHED_FENCE();
    #pragma unroll
    for (int kk = 0; kk < 2; kk++) {
      bf16x8 af[2], bfr[4];
      #pragma unroll
      for (int i = 0; i < 2; i++) {
        int R = mh * 32 + i * 16 + lr;
        int ch = (kk * 4 + lq) ^ (R & 7);
        af[i] = *(const bf16x8*)(as + R * 64 + ch * 8);
      }
      #pragma unroll
      for (int j = 0; j < 4; j++) {
        int R = nh * 64 + j * 16 + lr;
        int ch = (kk * 4 + lq) ^ (R & 7);
        bfr[j] = *(const bf16x8*)(bs + R * 64 + ch * 8);
      }
      __builtin_amdgcn_s_setprio(1);
      #pragma unroll
      for (int i = 0; i < 2; i++)
        #pragma unroll
        for (int j = 0; j < 4; j++)
          acc[i][j] = mfma16(af[i], bfr[j], acc[i][j]);
      __builtin_amdgcn_s_setprio(0);
    }
    WAIT_VM0();
    RAW_BAR();
  }

  #pragma unroll
  for (int i = 0; i < 2; i++) {
    #pragma unroll
    for (int j = 0; j < 4; j++) {
      int col = blockIdx.y * 128 + nh * 64 + j * 16 + lr;
      float bz = bias[col];
      #pragma unroll
      for (int r = 0; r < 4; r++) {
        int row = blockIdx.x * 64 + mh * 32 + i * 16 + lq * 4 + r;
        out[(size_t)row * 1024 + col] = acc[i][j][r] + bz;
      }
    }
  }
}

// ---------------- launch ----------------
extern "C" void kernel_launch(void* const* d_in, const int* in_sizes, int n_in,
                              void* d_out, int out_size, void* d_ws, size_t ws_size,
                              hipStream_t stream) {
  (void)in_sizes; (void)n_in; (void)out_size;
  const float* V  = (const float*)d_in[0];
  const float* Kx = (const float*)d_in[1];
  const float* Q  = (const float*)d_in[2];
  const float* Wv = (const float*)d_in[3];
  const float* bv = (const float*)d_in[4];
  const float* Wk = (const float*)d_in[5];
  const float* bk = (const float*)d_in[6];
  const float* Wq = (const float*)d_in[7];
  const float* bq = (const float*)d_in[8];
  const float* Wo = (const float*)d_in[9];
  const float* bo = (const float*)d_in[10];

  const size_t E = 1048576;
  if (ws_size < 20 * E * sizeof(bf16_t)) return;  // 40 MB needed

  bf16_t* ws = (bf16_t*)d_ws;
  bf16_t* cWo   = ws;            // 1E
  bf16_t* cWv   = ws + E;        // 1E
  bf16_t* cWk   = ws + 2 * E;    // 1E
  bf16_t* cWq   = ws + 3 * E;    // 1E
  bf16_t* q_ws  = ws + 4 * E;    // 4E  [bh][s][e], pre-scaled by 0.125*log2(e)
  bf16_t* k_ws  = ws + 8 * E;    // 4E  [bh][s][e]
  bf16_t* vt_ws = ws + 12 * E;   // 4E  [bh][e][s_perm]
  bf16_t* att_ws= ws + 16 * E;   // 4E  [b][s][h*64+e]

  bf16_t* cV = att_ws;                         // 8 MB (dead until attn)
  bf16_t* cK = (bf16_t*)d_out;                 // 8 MB (dead until gemm_out)
  bf16_t* cQ = (bf16_t*)d_out + 4 * E;         // 8 MB

  CvtArgs ca;
  ca.src[0] = Wo; ca.src[1] = Wv; ca.src[2] = Wk; ca.src[3] = Wq;
  ca.src[4] = V;  ca.src[5] = Kx; ca.src[6] = Q;
  ca.dst[0] = cWo; ca.dst[1] = cWv; ca.dst[2] = cWk; ca.dst[3] = cWq;
  ca.dst[4] = cV;  ca.dst[5] = cK;  ca.dst[6] = cQ;
  convert_all<<<8192, 256, 0, stream>>>(ca);

  ProjArgs pa;
  pa.A[0] = cV;  pa.A[1] = cK;  pa.A[2] = cQ;
  pa.W[0] = cWv; pa.W[1] = cWk; pa.W[2] = cWq;
  pa.bias[0] = bv; pa.bias[1] = bk; pa.bias[2] = bq;
  pa.out[0] = vt_ws; pa.out[1] = k_ws; pa.out[2] = q_ws;
  // Q pre-scale folds softmax's log2(e): exp(s/8) == 2^(s * 0.125 * log2e)
  pa.scale[0] = 1.f; pa.scale[1] = 1.f; pa.scale[2] = 0.125f * 1.4426950408889634f;
  gemm_proj<<<dim3(32, 8, 3), 256, 0, stream>>>(pa);

  attn<<<dim3(32, 32), 256, 0, stream>>>(q_ws, k_ws, vt_ws, att_ws);

  gemm_out<<<dim3(64, 8), 256, 0, stream>>>(att_ws, cWo, bo, (float*)d_out);
}

// Round 3
// 205.414 us; speedup vs baseline: 1.0515x; 1.0002x over previous
//
#include <hip/hip_runtime.h>
#include <cstdint>
#include <cstddef>

typedef __bf16 bf16_t;
typedef bf16_t bf16x8 __attribute__((ext_vector_type(8)));
typedef bf16_t bf16x4 __attribute__((ext_vector_type(4)));
typedef float f32x4 __attribute__((ext_vector_type(4)));
typedef float f32x2 __attribute__((ext_vector_type(2)));

__device__ __forceinline__ void gl_lds16(const void* g, void* l) {
  __builtin_amdgcn_global_load_lds(
      (const __attribute__((address_space(1))) void*)g,
      (__attribute__((address_space(3))) void*)l, 16, 0, 0);
}

__device__ __forceinline__ f32x4 mfma16(bf16x8 a, bf16x8 b, f32x4 c) {
  return __builtin_amdgcn_mfma_f32_16x16x32_bf16(a, b, c, 0, 0, 0);
}

// 2^x in one TRANS op (log2e is pre-folded into the Q scale).
__device__ __forceinline__ float exp2_fast(float x) {
  float r;
  asm("v_exp_f32 %0, %1" : "=v"(r) : "v"(x));
  return r;
}

// Scheduling fences: rule #18 — pin inline-asm waitcnts and raw barriers.
#define SCHED_FENCE() __builtin_amdgcn_sched_barrier(0)
#define WAIT_VM0()   do { asm volatile("s_waitcnt vmcnt(0)");   SCHED_FENCE(); } while (0)
#define WAIT_LGKM0() do { asm volatile("s_waitcnt lgkmcnt(0)"); SCHED_FENCE(); } while (0)
#define RAW_BAR()    do { __builtin_amdgcn_s_barrier();         SCHED_FENCE(); } while (0)

// ---------------- fp32 -> bf16 convert: 4 weights (1M elems) + 3 activations (4M) ---
struct CvtArgs { const float* src[7]; bf16_t* dst[7]; };

__global__ __launch_bounds__(256) void convert_all(CvtArgs a) {
  unsigned g = blockIdx.x * 256u + threadIdx.x;   // 2,097,152 groups of 8
  unsigned seg, off;
  if (g < 524288u) {            // weights: 4 x 131072 groups
    seg = g >> 17; off = g & 131071u;
  } else {                      // activations: 3 x 524288 groups
    unsigned h = g - 524288u;
    seg = 4u + (h >> 19); off = h & 524287u;
  }
  const float4* s = (const float4*)a.src[seg] + (size_t)off * 2;
  float4 x0 = s[0], x1 = s[1];
  bf16x8 o;
  o[0] = (bf16_t)x0.x; o[1] = (bf16_t)x0.y; o[2] = (bf16_t)x0.z; o[3] = (bf16_t)x0.w;
  o[4] = (bf16_t)x1.x; o[5] = (bf16_t)x1.y; o[6] = (bf16_t)x1.z; o[7] = (bf16_t)x1.w;
  *(bf16x8*)(a.dst[seg] + (size_t)off * 8) = o;
}

// ---------------- staging helpers (pre-swizzled global source, linear LDS dest) ----
__device__ __forceinline__ void stage128(const bf16_t* src, bf16_t* dst, int t, int w) {
  #pragma unroll
  for (int i = 0; i < 4; i++) {
    int g = t + i * 256;
    int r = g >> 3, pc = g & 7;
    int lc = pc ^ (r & 7);
    gl_lds16(src + (size_t)r * 1024 + lc * 8, dst + i * 2048 + w * 512);
  }
}
__device__ __forceinline__ void stage64(const bf16_t* src, bf16_t* dst, int t, int w) {
  #pragma unroll
  for (int i = 0; i < 2; i++) {
    int g = t + i * 256;
    int r = g >> 3, pc = g & 7;
    int lc = pc ^ (r & 7);
    gl_lds16(src + (size_t)r * 1024 + lc * 8, dst + i * 2048 + w * 512);
  }
}

// ---------------- fused QKV projection (A bf16, W bf16, out bf16) ----------------
// z=0: V -> vt [bh][e][s_perm]; z=1: K -> [bh][s][e]; z=2: Q -> [bh][s][e]*qscale
struct ProjArgs {
  const bf16_t* A[3]; const bf16_t* W[3]; const float* bias[3];
  bf16_t* out[3]; float scale[3];
};

__global__ __launch_bounds__(256, 2) void gemm_proj(ProjArgs p) {
  __shared__ __attribute__((aligned(16))) unsigned char smem[65536];
  const int z = blockIdx.z;
  const bf16_t* A = p.A[z] + (size_t)blockIdx.x * 128 * 1024;
  const bf16_t* W = p.W[z] + (size_t)blockIdx.y * 128 * 1024;

  const int t = threadIdx.x;
  const int w = t >> 6, l = t & 63;
  const int lq = l >> 4, lr = l & 15;
  const int mq = w & 1, nq = w >> 1;

  f32x4 acc[4][4];
  f32x4 zero = {0.f, 0.f, 0.f, 0.f};
  #pragma unroll
  for (int i = 0; i < 4; i++)
    #pragma unroll
    for (int j = 0; j < 4; j++) acc[i][j] = zero;

  stage128(A, (bf16_t*)smem, t, w);
  stage128(W, (bf16_t*)(smem + 16384), t, w);
  WAIT_VM0();
  RAW_BAR();

  for (int step = 0; step < 16; ++step) {
    const int cur = step & 1;
    bf16_t* as = (bf16_t*)(smem + cur * 32768);
    bf16_t* bs = (bf16_t*)(smem + cur * 32768 + 16384);
    if (step < 15) {
      bf16_t* an = (bf16_t*)(smem + (cur ^ 1) * 32768);
      stage128(A + (step + 1) * 64, an, t, w);
      stage128(W + (step + 1) * 64, an + 8192, t, w);
    }
    SCHED_FENCE();
    #pragma unroll
    for (int kk = 0; kk < 2; kk++) {
      bf16x8 af[4], bfr[4];
      #pragma unroll
      for (int i = 0; i < 4; i++) {
        int R = mq * 64 + i * 16 + lr;
        int ch = (kk * 4 + lq) ^ (R & 7);
        af[i] = *(const bf16x8*)(as + R * 64 + ch * 8);
      }
      #pragma unroll
      for (int j = 0; j < 4; j++) {
        int R = nq * 64 + j * 16 + lr;
        int ch = (kk * 4 + lq) ^ (R & 7);
        bfr[j] = *(const bf16x8*)(bs + R * 64 + ch * 8);
      }
      __builtin_amdgcn_s_setprio(1);
      #pragma unroll
      for (int i = 0; i < 4; i++)
        #pragma unroll
        for (int j = 0; j < 4; j++)
          acc[i][j] = mfma16(af[i], bfr[j], acc[i][j]);
      __builtin_amdgcn_s_setprio(0);
    }
    WAIT_VM0();
    RAW_BAR();
  }

  const float* bias = p.bias[z];
  const float scale = p.scale[z];
  __syncthreads();
  bf16_t* ts = (bf16_t*)smem;  // 128 x 136 bf16 = 34,816 B
  #pragma unroll
  for (int i = 0; i < 4; i++) {
    #pragma unroll
    for (int j = 0; j < 4; j++) {
      int nl = nq * 64 + j * 16 + lr;
      float bz = bias[blockIdx.y * 128 + nl];
      #pragma unroll
      for (int r = 0; r < 4; r++) {
        int ml = mq * 64 + i * 16 + lq * 4 + r;
        bf16_t val = (bf16_t)((acc[i][j][r] + bz) * scale);
        if (z == 0) {
          int mlp = (ml & 96) | (((ml >> 2) & 3) << 3) | (((ml >> 4) & 1) << 2) | (ml & 3);
          ts[nl * 136 + mlp] = val;   // transposed (+permuted) for vt
        } else {
          ts[ml * 136 + nl] = val;
        }
      }
    }
  }
  __syncthreads();
  bf16_t* out = p.out[z];
  const int b = blockIdx.x >> 4, sbase = (blockIdx.x & 15) * 128;
  if (z == 0) {
    #pragma unroll
    for (int ii = 0; ii < 8; ii++) {
      int idx = t * 8 + ii * 2048;
      int rr = idx >> 7, cc = idx & 127;
      int n = blockIdx.y * 128 + rr;
      int h = n >> 6, e = n & 63;
      bf16x8 vq = *(const bf16x8*)(ts + rr * 136 + cc);
      *(bf16x8*)(out + ((size_t)(b * 16 + h) * 64 + e) * 2048 + sbase + cc) = vq;
    }
  } else {
    #pragma unroll
    for (int ii = 0; ii < 8; ii++) {
      int idx = t * 8 + ii * 2048;
      int rr = idx >> 7, cc = idx & 127;
      int n = blockIdx.y * 128 + cc;
      int h = n >> 6, e = n & 63;
      bf16x8 vq = *(const bf16x8*)(ts + rr * 136 + cc);
      *(bf16x8*)(out + ((size_t)(b * 16 + h) * 2048 + sbase + rr) * 64 + e) = vq;
    }
  }
}

// ---------------- flash attention, S^T formulation -----------------------------
// R3: Mq=32 — each wave owns TWO 16-q groups, so one K/V fragment read feeds two
// MFMAs. CU-level LDS read traffic halves (was the R2 wall: 16 waves x 16 b128 x
// 12cyc = 3072 cyc/iter ~= measured 45.6us). Block = 4 waves x 32 q = 128 q;
// grid (32 bh, 16 qt) = 512 blocks = 2/CU. Q tile (128x64=16KB) stages into buf1,
// secured to 8 loop-invariant reg frags, then buf1 recycles as K/V double-buffer.
// Deferred-PV pipeline (R2) retained.
__global__ __launch_bounds__(256, 2) void attn(
    const bf16_t* __restrict__ qw, const bf16_t* __restrict__ kw,
    const bf16_t* __restrict__ vtw, bf16_t* __restrict__ att)
{
  __shared__ __attribute__((aligned(16))) unsigned char smem[32768];
  // buf0 = [k:0..8K | v:8K..16K], buf1 = [16K..24K | 24K..32K]
  const int bh = blockIdx.x, qt = blockIdx.y;
  const int t = threadIdx.x, w = t >> 6, l = t & 63, lq = l >> 4, lr = l & 15;

  const bf16_t* kb0 = kw + (size_t)bh * 131072;
  const bf16_t* vb0 = vtw + (size_t)bh * 131072;
  bf16_t* qstage = (bf16_t*)(smem + 16384);   // Q tile 128x64 = 16 KB = buf1

  // prologue: Q tile -> buf1, K/V tile 0 -> buf0
  const bf16_t* qbase = qw + ((size_t)bh * 2048 + qt * 128) * 64;
  #pragma unroll
  for (int i = 0; i < 4; i++) {
    int g = t + i * 256;
    int r = g >> 3, pc = g & 7;
    int lc = pc ^ (r & 7);
    gl_lds16(qbase + (size_t)r * 64 + lc * 8, qstage + i * 2048 + w * 512);
  }
  #pragma unroll
  for (int i = 0; i < 2; i++) {
    int g = t + i * 256;
    int r = g >> 3, pc = g & 7;
    int lc = pc ^ (r & 7);
    gl_lds16(kb0 + (size_t)r * 64 + lc * 8, (bf16_t*)smem + i * 2048 + w * 512);
    gl_lds16(vb0 + (size_t)r * 2048 + lc * 8, (bf16_t*)(smem + 8192) + i * 2048 + w * 512);
  }
  WAIT_VM0();
  RAW_BAR();
  bf16x8 qf[2][2];
  #pragma unroll
  for (int gq = 0; gq < 2; gq++)
    #pragma unroll
    for (int kk = 0; kk < 2; kk++) {
      int R = w * 32 + gq * 16 + lr;
      int ch = (kk * 4 + lq) ^ (R & 7);
      qf[gq][kk] = *(const bf16x8*)(qstage + R * 64 + ch * 8);
    }
  WAIT_LGKM0();   // Q secured in regs before buf1 (alias) is overwritten
  RAW_BAR();

  f32x4 O[2][4];
  f32x4 zero = {0.f, 0.f, 0.f, 0.f};
  #pragma unroll
  for (int gq = 0; gq < 2; gq++)
    #pragma unroll
    for (int et = 0; et < 4; et++) O[gq][et] = zero;
  f32x2 lsv[2];
  lsv[0] = f32x2{0.f, 0.f}; lsv[1] = f32x2{0.f, 0.f};
  bf16x8 vf[8];             // V-frags of current tile (consumed by NEXT iter's PV)
  bf16x8 pbA[2][2], pbB[2][2];

#define ATTN_BODY(KT, CUR, PBOUT, PBIN, FIRST, DOSTAGE)                          \
  {                                                                              \
    bf16_t* ksb = (bf16_t*)(smem + (CUR) * 16384);                               \
    bf16_t* vsb = (bf16_t*)(smem + (CUR) * 16384 + 8192);                        \
    if (DOSTAGE) {                                                               \
      bf16_t* kn = (bf16_t*)(smem + ((CUR) ^ 1) * 16384);                        \
      const bf16_t* kbase = kb0 + (size_t)((KT) + 1) * 4096;                     \
      const bf16_t* vbase = vb0 + (size_t)((KT) + 1) * 64;                       \
      _Pragma("unroll")                                                          \
      for (int i = 0; i < 2; i++) {                                              \
        int g = t + i * 256;                                                     \
        int r = g >> 3, pc = g & 7;                                              \
        int lc = pc ^ (r & 7);                                                   \
        gl_lds16(kbase + (size_t)r * 64 + lc * 8, kn + i * 2048 + w * 512);      \
        gl_lds16(vbase + (size_t)r * 2048 + lc * 8, kn + 4096 + i * 2048 + w * 512); \
      }                                                                          \
    }                                                                            \
    f32x4 sc[2][4];                                                              \
    _Pragma("unroll")                                                            \
    for (int gq = 0; gq < 2; gq++)                                               \
      _Pragma("unroll")                                                          \
      for (int j = 0; j < 4; j++) sc[gq][j] = zero;                              \
    __builtin_amdgcn_s_setprio(1);                                               \
    if (!(FIRST)) {                                                              \
      _Pragma("unroll")                                                          \
      for (int ks2 = 0; ks2 < 2; ks2++)                                          \
        _Pragma("unroll")                                                        \
        for (int et = 0; et < 4; et++) {                                         \
          O[0][et] = mfma16(vf[ks2 * 4 + et], (PBIN)[0][ks2], O[0][et]);         \
          O[1][et] = mfma16(vf[ks2 * 4 + et], (PBIN)[1][ks2], O[1][et]);         \
        }                                                                        \
    }                                                                            \
    _Pragma("unroll")                                                            \
    for (int kk = 0; kk < 2; kk++)                                               \
      _Pragma("unroll")                                                          \
      for (int j = 0; j < 4; j++) {                                              \
        int R = j * 16 + lr;                                                     \
        int ch = (kk * 4 + lq) ^ (R & 7);                                        \
        bf16x8 kf = *(const bf16x8*)(ksb + R * 64 + ch * 8);                     \
        sc[0][j] = mfma16(kf, qf[0][kk], sc[0][j]);                              \
        sc[1][j] = mfma16(kf, qf[1][kk], sc[1][j]);                              \
      }                                                                          \
    __builtin_amdgcn_s_setprio(0);                                               \
    _Pragma("unroll")                                                            \
    for (int ks2 = 0; ks2 < 2; ks2++)                                            \
      _Pragma("unroll")                                                          \
      for (int et = 0; et < 4; et++) {                                           \
        int R = et * 16 + lr;                                                    \
        int ch = (ks2 * 4 + lq) ^ (R & 7);                                       \
        vf[ks2 * 4 + et] = *(const bf16x8*)(vsb + R * 64 + ch * 8);              \
      }                                                                          \
    _Pragma("unroll")                                                            \
    for (int gq = 0; gq < 2; gq++)                                               \
      _Pragma("unroll")                                                          \
      for (int ks2 = 0; ks2 < 2; ks2++)                                          \
        _Pragma("unroll")                                                        \
        for (int r = 0; r < 4; r++) {                                            \
          float e0 = exp2_fast(sc[gq][2 * ks2][r]);                              \
          float e1 = exp2_fast(sc[gq][2 * ks2 + 1][r]);                          \
          f32x2 ee = {e0, e1};                                                   \
          lsv[gq] += ee;                                                         \
          (PBOUT)[gq][ks2][r] = (bf16_t)e0;                                      \
          (PBOUT)[gq][ks2][4 + r] = (bf16_t)e1;                                  \
        }                                                                        \
    WAIT_LGKM0();     /* vf + kf reads retired before buffer can be reused */    \
    if (DOSTAGE) WAIT_VM0(); /* stage(KT+1) landed */                            \
    RAW_BAR();                                                                   \
  }

  ATTN_BODY(0, 0, pbA, pbB, true, true);
  ATTN_BODY(1, 1, pbB, pbA, false, true);
  for (int kt2 = 1; kt2 < 16; ++kt2) {
    const int kt = kt2 * 2;
    ATTN_BODY(kt, 0, pbA, pbB, false, true);
    ATTN_BODY(kt + 1, 1, pbB, pbA, false, (kt2 < 15));
  }
#undef ATTN_BODY

  // epilogue PV: tile 31 (pbB + vf)
  #pragma unroll
  for (int ks2 = 0; ks2 < 2; ks2++)
    #pragma unroll
    for (int et = 0; et < 4; et++) {
      O[0][et] = mfma16(vf[ks2 * 4 + et], pbB[0][ks2], O[0][et]);
      O[1][et] = mfma16(vf[ks2 * 4 + et], pbB[1][ks2], O[1][et]);
    }

  float s0 = lsv[0][0] + lsv[0][1];
  float s1 = lsv[1][0] + lsv[1][1];
  s0 += __shfl_xor(s0, 16);
  s0 += __shfl_xor(s0, 32);
  s1 += __shfl_xor(s1, 16);
  s1 += __shfl_xor(s1, 32);
  float rinv[2] = {1.0f / s0, 1.0f / s1};

  // epilogue: LDS transpose (128 x 72 pitch = 18.4 KB at smem base; all K/V
  // buffer reads drained by the final RAW_BAR) then coalesced store.
  bf16_t* ts = (bf16_t*)smem;
  #pragma unroll
  for (int gq = 0; gq < 2; gq++)
    #pragma unroll
    for (int et = 0; et < 4; et++) {
      bf16x4 pv;
      #pragma unroll
      for (int r = 0; r < 4; r++) pv[r] = (bf16_t)(O[gq][et][r] * rinv[gq]);
      *(bf16x4*)(ts + (w * 32 + gq * 16 + lr) * 72 + et * 16 + lq * 4) = pv;
    }
  __syncthreads();
  const int b = bh >> 4, h = bh & 15;
  #pragma unroll
  for (int i = 0; i < 4; i++) {
    int c = t + i * 256;
    int row = c >> 3, c8 = c & 7;
    bf16x8 vv = *(const bf16x8*)(ts + row * 72 + c8 * 8);
    *(bf16x8*)(att + ((size_t)b * 2048 + qt * 128 + row) * 1024 + h * 64 + c8 * 8) = vv;
  }
}

// ---------------- output projection (A bf16, W bf16, out fp32) ----------------
__global__ __launch_bounds__(256, 3) void gemm_out(
    const bf16_t* __restrict__ A, const bf16_t* __restrict__ W,
    const float* __restrict__ bias, float* __restrict__ out)
{
  __shared__ __attribute__((aligned(16))) unsigned char smem[49152];
  const bf16_t* Ab = A + (size_t)blockIdx.x * 64 * 1024;
  const bf16_t* Wb = W + (size_t)blockIdx.y * 128 * 1024;
  const int t = threadIdx.x, w = t >> 6, l = t & 63, lq = l >> 4, lr = l & 15;
  const int mh = w & 1, nh = w >> 1;

  f32x4 acc[2][4];
  f32x4 zero = {0.f, 0.f, 0.f, 0.f};
  #pragma unroll
  for (int i = 0; i < 2; i++)
    #pragma unroll
    for (int j = 0; j < 4; j++) acc[i][j] = zero;

  stage64(Ab, (bf16_t*)smem, t, w);
  stage128(Wb, (bf16_t*)(smem + 8192), t, w);
  WAIT_VM0();
  RAW_BAR();

  for (int step = 0; step < 16; ++step) {
    const int cur = step & 1;
    bf16_t* as = (bf16_t*)(smem + cur * 24576);
    bf16_t* bs = (bf16_t*)(smem + cur * 24576 + 8192);
    if (step < 15) {
      bf16_t* an = (bf16_t*)(smem + (cur ^ 1) * 24576);
      stage64(Ab + (step + 1) * 64, an, t, w);
      stage128(Wb + (step + 1) * 64, an + 4096, t, w);
    }
    SCHED_FENCE();
    #pragma unroll
    for (int kk = 0; kk < 2; kk++) {
      bf16x8 af[2], bfr[4];
      #pragma unroll
      for (int i = 0; i < 2; i++) {
        int R = mh * 32 + i * 16 + lr;
        int ch = (kk * 4 + lq) ^ (R & 7);
        af[i] = *(const bf16x8*)(as + R * 64 + ch * 8);
      }
      #pragma unroll
      for (int j = 0; j < 4; j++) {
        int R = nh * 64 + j * 16 + lr;
        int ch = (kk * 4 + lq) ^ (R & 7);
        bfr[j] = *(const bf16x8*)(bs + R * 64 + ch * 8);
      }
      __builtin_amdgcn_s_setprio(1);
      #pragma unroll
      for (int i = 0; i < 2; i++)
        #pragma unroll
        for (int j = 0; j < 4; j++)
          acc[i][j] = mfma16(af[i], bfr[j], acc[i][j]);
      __builtin_amdgcn_s_setprio(0);
    }
    WAIT_VM0();
    RAW_BAR();
  }

  #pragma unroll
  for (int i = 0; i < 2; i++) {
    #pragma unroll
    for (int j = 0; j < 4; j++) {
      int col = blockIdx.y * 128 + nh * 64 + j * 16 + lr;
      float bz = bias[col];
      #pragma unroll
      for (int r = 0; r < 4; r++) {
        int row = blockIdx.x * 64 + mh * 32 + i * 16 + lq * 4 + r;
        out[(size_t)row * 1024 + col] = acc[i][j][r] + bz;
      }
    }
  }
}

// ---------------- launch ----------------
extern "C" void kernel_launch(void* const* d_in, const int* in_sizes, int n_in,
                              void* d_out, int out_size, void* d_ws, size_t ws_size,
                              hipStream_t stream) {
  (void)in_sizes; (void)n_in; (void)out_size;
  const float* V  = (const float*)d_in[0];
  const float* Kx = (const float*)d_in[1];
  const float* Q  = (const float*)d_in[2];
  const float* Wv = (const float*)d_in[3];
  const float* bv = (const float*)d_in[4];
  const float* Wk = (const float*)d_in[5];
  const float* bk = (const float*)d_in[6];
  const float* Wq = (const float*)d_in[7];
  const float* bq = (const float*)d_in[8];
  const float* Wo = (const float*)d_in[9];
  const float* bo = (const float*)d_in[10];

  const size_t E = 1048576;
  if (ws_size < 20 * E * sizeof(bf16_t)) return;  // 40 MB needed

  bf16_t* ws = (bf16_t*)d_ws;
  bf16_t* cWo   = ws;            // 1E
  bf16_t* cWv   = ws + E;        // 1E
  bf16_t* cWk   = ws + 2 * E;    // 1E
  bf16_t* cWq   = ws + 3 * E;    // 1E
  bf16_t* q_ws  = ws + 4 * E;    // 4E  [bh][s][e], pre-scaled by 0.125*log2(e)
  bf16_t* k_ws  = ws + 8 * E;    // 4E  [bh][s][e]
  bf16_t* vt_ws = ws + 12 * E;   // 4E  [bh][e][s_perm]
  bf16_t* att_ws= ws + 16 * E;   // 4E  [b][s][h*64+e]

  bf16_t* cV = att_ws;                         // 8 MB (dead until attn)
  bf16_t* cK = (bf16_t*)d_out;                 // 8 MB (dead until gemm_out)
  bf16_t* cQ = (bf16_t*)d_out + 4 * E;         // 8 MB

  CvtArgs ca;
  ca.src[0] = Wo; ca.src[1] = Wv; ca.src[2] = Wk; ca.src[3] = Wq;
  ca.src[4] = V;  ca.src[5] = Kx; ca.src[6] = Q;
  ca.dst[0] = cWo; ca.dst[1] = cWv; ca.dst[2] = cWk; ca.dst[3] = cWq;
  ca.dst[4] = cV;  ca.dst[5] = cK;  ca.dst[6] = cQ;
  convert_all<<<8192, 256, 0, stream>>>(ca);

  ProjArgs pa;
  pa.A[0] = cV;  pa.A[1] = cK;  pa.A[2] = cQ;
  pa.W[0] = cWv; pa.W[1] = cWk; pa.W[2] = cWq;
  pa.bias[0] = bv; pa.bias[1] = bk; pa.bias[2] = bq;
  pa.out[0] = vt_ws; pa.out[1] = k_ws; pa.out[2] = q_ws;
  // Q pre-scale folds softmax's log2(e): exp(s/8) == 2^(s * 0.125 * log2e)
  pa.scale[0] = 1.f; pa.scale[1] = 1.f; pa.scale[2] = 0.125f * 1.4426950408889634f;
  gemm_proj<<<dim3(32, 8, 3), 256, 0, stream>>>(pa);

  attn<<<dim3(32, 16), 256, 0, stream>>>(q_ws, k_ws, vt_ws, att_ws);

  gemm_out<<<dim3(64, 8), 256, 0, stream>>>(att_ws, cWo, bo, (float*)d_out);
}

// Round 5
// 204.709 us; speedup vs baseline: 1.0551x; 1.0034x over previous
//
#include <hip/hip_runtime.h>
#include <cstdint>
#include <cstddef>

typedef __bf16 bf16_t;
typedef bf16_t bf16x8 __attribute__((ext_vector_type(8)));
typedef bf16_t bf16x4 __attribute__((ext_vector_type(4)));
typedef float f32x4 __attribute__((ext_vector_type(4)));
typedef float f32x2 __attribute__((ext_vector_type(2)));

__device__ __forceinline__ void gl_lds16(const void* g, void* l) {
  __builtin_amdgcn_global_load_lds(
      (const __attribute__((address_space(1))) void*)g,
      (__attribute__((address_space(3))) void*)l, 16, 0, 0);
}

__device__ __forceinline__ f32x4 mfma16(bf16x8 a, bf16x8 b, f32x4 c) {
  return __builtin_amdgcn_mfma_f32_16x16x32_bf16(a, b, c, 0, 0, 0);
}

// 2^x in one TRANS op (log2e is pre-folded into the Q scale).
__device__ __forceinline__ float exp2_fast(float x) {
  float r;
  asm("v_exp_f32 %0, %1" : "=v"(r) : "v"(x));
  return r;
}

// Scheduling fences: rule #18 — pin inline-asm waitcnts and raw barriers.
#define SCHED_FENCE() __builtin_amdgcn_sched_barrier(0)
#define WAIT_VM0()   do { asm volatile("s_waitcnt vmcnt(0)");   SCHED_FENCE(); } while (0)
#define WAIT_LGKM0() do { asm volatile("s_waitcnt lgkmcnt(0)"); SCHED_FENCE(); } while (0)
#define RAW_BAR()    do { __builtin_amdgcn_s_barrier();         SCHED_FENCE(); } while (0)

// ---------------- fp32 -> bf16 convert: 4 weights (1M elems) + 3 activations (4M) ---
struct CvtArgs { const float* src[7]; bf16_t* dst[7]; };

__global__ __launch_bounds__(256) void convert_all(CvtArgs a) {
  unsigned g = blockIdx.x * 256u + threadIdx.x;   // 2,097,152 groups of 8
  unsigned seg, off;
  if (g < 524288u) {            // weights: 4 x 131072 groups
    seg = g >> 17; off = g & 131071u;
  } else {                      // activations: 3 x 524288 groups
    unsigned h = g - 524288u;
    seg = 4u + (h >> 19); off = h & 524287u;
  }
  const float4* s = (const float4*)a.src[seg] + (size_t)off * 2;
  float4 x0 = s[0], x1 = s[1];
  bf16x8 o;
  o[0] = (bf16_t)x0.x; o[1] = (bf16_t)x0.y; o[2] = (bf16_t)x0.z; o[3] = (bf16_t)x0.w;
  o[4] = (bf16_t)x1.x; o[5] = (bf16_t)x1.y; o[6] = (bf16_t)x1.z; o[7] = (bf16_t)x1.w;
  *(bf16x8*)(a.dst[seg] + (size_t)off * 8) = o;
}

// ---------------- staging helpers (pre-swizzled global source, linear LDS dest) ----
__device__ __forceinline__ void stage128(const bf16_t* src, bf16_t* dst, int t, int w) {
  #pragma unroll
  for (int i = 0; i < 4; i++) {
    int g = t + i * 256;
    int r = g >> 3, pc = g & 7;
    int lc = pc ^ (r & 7);
    gl_lds16(src + (size_t)r * 1024 + lc * 8, dst + i * 2048 + w * 512);
  }
}
__device__ __forceinline__ void stage64(const bf16_t* src, bf16_t* dst, int t, int w) {
  #pragma unroll
  for (int i = 0; i < 2; i++) {
    int g = t + i * 256;
    int r = g >> 3, pc = g & 7;
    int lc = pc ^ (r & 7);
    gl_lds16(src + (size_t)r * 1024 + lc * 8, dst + i * 2048 + w * 512);
  }
}

// ---------------- fused QKV projection (A bf16, W bf16, out bf16) ----------------
// z=0: V -> vt [bh][e][s_perm]; z=1: K -> [bh][s][e]; z=2: Q -> [bh][s][e]*qscale
struct ProjArgs {
  const bf16_t* A[3]; const bf16_t* W[3]; const float* bias[3];
  bf16_t* out[3]; float scale[3];
};

__global__ __launch_bounds__(256, 2) void gemm_proj(ProjArgs p) {
  __shared__ __attribute__((aligned(16))) unsigned char smem[65536];
  const int z = blockIdx.z;
  const bf16_t* A = p.A[z] + (size_t)blockIdx.x * 128 * 1024;
  const bf16_t* W = p.W[z] + (size_t)blockIdx.y * 128 * 1024;

  const int t = threadIdx.x;
  const int w = t >> 6, l = t & 63;
  const int lq = l >> 4, lr = l & 15;
  const int mq = w & 1, nq = w >> 1;

  f32x4 acc[4][4];
  f32x4 zero = {0.f, 0.f, 0.f, 0.f};
  #pragma unroll
  for (int i = 0; i < 4; i++)
    #pragma unroll
    for (int j = 0; j < 4; j++) acc[i][j] = zero;

  stage128(A, (bf16_t*)smem, t, w);
  stage128(W, (bf16_t*)(smem + 16384), t, w);
  WAIT_VM0();
  RAW_BAR();

  for (int step = 0; step < 16; ++step) {
    const int cur = step & 1;
    bf16_t* as = (bf16_t*)(smem + cur * 32768);
    bf16_t* bs = (bf16_t*)(smem + cur * 32768 + 16384);
    if (step < 15) {
      bf16_t* an = (bf16_t*)(smem + (cur ^ 1) * 32768);
      stage128(A + (step + 1) * 64, an, t, w);
      stage128(W + (step + 1) * 64, an + 8192, t, w);
    }
    SCHED_FENCE();
    #pragma unroll
    for (int kk = 0; kk < 2; kk++) {
      bf16x8 af[4], bfr[4];
      #pragma unroll
      for (int i = 0; i < 4; i++) {
        int R = mq * 64 + i * 16 + lr;
        int ch = (kk * 4 + lq) ^ (R & 7);
        af[i] = *(const bf16x8*)(as + R * 64 + ch * 8);
      }
      #pragma unroll
      for (int j = 0; j < 4; j++) {
        int R = nq * 64 + j * 16 + lr;
        int ch = (kk * 4 + lq) ^ (R & 7);
        bfr[j] = *(const bf16x8*)(bs + R * 64 + ch * 8);
      }
      __builtin_amdgcn_s_setprio(1);
      #pragma unroll
      for (int i = 0; i < 4; i++)
        #pragma unroll
        for (int j = 0; j < 4; j++)
          acc[i][j] = mfma16(af[i], bfr[j], acc[i][j]);
      __builtin_amdgcn_s_setprio(0);
    }
    WAIT_VM0();
    RAW_BAR();
  }

  const float* bias = p.bias[z];
  const float scale = p.scale[z];
  __syncthreads();
  bf16_t* ts = (bf16_t*)smem;  // 128 x 136 bf16 = 34,816 B
  #pragma unroll
  for (int i = 0; i < 4; i++) {
    #pragma unroll
    for (int j = 0; j < 4; j++) {
      int nl = nq * 64 + j * 16 + lr;
      float bz = bias[blockIdx.y * 128 + nl];
      #pragma unroll
      for (int r = 0; r < 4; r++) {
        int ml = mq * 64 + i * 16 + lq * 4 + r;
        bf16_t val = (bf16_t)((acc[i][j][r] + bz) * scale);
        if (z == 0) {
          int mlp = (ml & 96) | (((ml >> 2) & 3) << 3) | (((ml >> 4) & 1) << 2) | (ml & 3);
          ts[nl * 136 + mlp] = val;   // transposed (+permuted) for vt
        } else {
          ts[ml * 136 + nl] = val;
        }
      }
    }
  }
  __syncthreads();
  bf16_t* out = p.out[z];
  const int b = blockIdx.x >> 4, sbase = (blockIdx.x & 15) * 128;
  if (z == 0) {
    #pragma unroll
    for (int ii = 0; ii < 8; ii++) {
      int idx = t * 8 + ii * 2048;
      int rr = idx >> 7, cc = idx & 127;
      int n = blockIdx.y * 128 + rr;
      int h = n >> 6, e = n & 63;
      bf16x8 vq = *(const bf16x8*)(ts + rr * 136 + cc);
      *(bf16x8*)(out + ((size_t)(b * 16 + h) * 64 + e) * 2048 + sbase + cc) = vq;
    }
  } else {
    #pragma unroll
    for (int ii = 0; ii < 8; ii++) {
      int idx = t * 8 + ii * 2048;
      int rr = idx >> 7, cc = idx & 127;
      int n = blockIdx.y * 128 + cc;
      int h = n >> 6, e = n & 63;
      bf16x8 vq = *(const bf16x8*)(ts + rr * 136 + cc);
      *(bf16x8*)(out + ((size_t)(b * 16 + h) * 2048 + sbase + rr) * 64 + e) = vq;
    }
  }
}

// ---------------- flash attention, S^T formulation -----------------------------
// R5: R4's 3-buffer 2-deep prefetch, with the RACE FIXED. R4 put the counted
// vmcnt AFTER the barrier (top of iteration) — vmcnt is per-wave, so a wave
// could read LDS written by ANOTHER wave's still-in-flight DMA. Correct
// handshake (as in gemm_proj and the 8-phase template): counted wait BEFORE the
// barrier. Body kt: issue stage(kt+2); PV(kt-1); QK(kt); vf-read(kt); softmax;
// s_waitcnt vmcnt(4) lgkmcnt(0)  [retires tile kt+1 = next read, leaves kt+2's
// 4 loads in flight across the barrier]; s_barrier. Loads issued at kt retire
// at end of kt+1 -> ~1.5 iterations of slack vs R3's same-iteration drain.
__global__ __launch_bounds__(256, 2) void attn(
    const bf16_t* __restrict__ qw, const bf16_t* __restrict__ kw,
    const bf16_t* __restrict__ vtw, bf16_t* __restrict__ att)
{
  __shared__ __attribute__((aligned(16))) unsigned char smem[49152];
  // buf_i = smem + i*16K = [K 8K | V 8K], i = 0,1,2; Q stages into buf2
  const int bh = blockIdx.x, qt = blockIdx.y;
  const int t = threadIdx.x, w = t >> 6, l = t & 63, lq = l >> 4, lr = l & 15;

  const bf16_t* kb0 = kw + (size_t)bh * 131072;
  const bf16_t* vb0 = vtw + (size_t)bh * 131072;
  bf16_t* qstage = (bf16_t*)(smem + 32768);   // buf2

  // prologue: Q -> buf2 (4 loads), K/V t0 -> buf0 (4), K/V t1 -> buf1 (4)
  const bf16_t* qbase = qw + ((size_t)bh * 2048 + qt * 128) * 64;
  #pragma unroll
  for (int i = 0; i < 4; i++) {
    int g = t + i * 256;
    int r = g >> 3, pc = g & 7;
    int lc = pc ^ (r & 7);
    gl_lds16(qbase + (size_t)r * 64 + lc * 8, qstage + i * 2048 + w * 512);
  }
  #pragma unroll
  for (int tt = 0; tt < 2; tt++) {
    bf16_t* kn = (bf16_t*)(smem + tt * 16384);
    const bf16_t* kbase = kb0 + (size_t)tt * 4096;
    const bf16_t* vbase = vb0 + (size_t)tt * 64;
    #pragma unroll
    for (int i = 0; i < 2; i++) {
      int g = t + i * 256;
      int r = g >> 3, pc = g & 7;
      int lc = pc ^ (r & 7);
      gl_lds16(kbase + (size_t)r * 64 + lc * 8, kn + i * 2048 + w * 512);
      gl_lds16(vbase + (size_t)r * 2048 + lc * 8, kn + 4096 + i * 2048 + w * 512);
    }
  }
  asm volatile("s_waitcnt vmcnt(8)");  // my Q loads retired; barrier -> all Q landed
  SCHED_FENCE();
  RAW_BAR();
  bf16x8 qf[2][2];
  #pragma unroll
  for (int gq = 0; gq < 2; gq++)
    #pragma unroll
    for (int kk = 0; kk < 2; kk++) {
      int R = w * 32 + gq * 16 + lr;
      int ch = (kk * 4 + lq) ^ (R & 7);
      qf[gq][kk] = *(const bf16x8*)(qstage + R * 64 + ch * 8);
    }
  // my tile-0 loads retired + my Q ds_reads done; barrier -> tile 0 landed
  // for ALL waves and buf2 is free to rejoin the rotation.
  asm volatile("s_waitcnt vmcnt(4) lgkmcnt(0)");
  SCHED_FENCE();
  RAW_BAR();

  f32x4 O[2][4];
  f32x4 zero = {0.f, 0.f, 0.f, 0.f};
  #pragma unroll
  for (int gq = 0; gq < 2; gq++)
    #pragma unroll
    for (int et = 0; et < 4; et++) O[gq][et] = zero;
  f32x2 lsv[2];
  lsv[0] = f32x2{0.f, 0.f}; lsv[1] = f32x2{0.f, 0.f};
  bf16x8 vfA[8], vfB[8];    // V-frag ping-pong (read at kt, consumed at kt+1)
  bf16x8 pbA[2][2], pbB[2][2];

#define ATTN_BODY(KT, BUF, NBUF, PBOUT, PBIN, VFOUT, VFIN, FIRST, DOSTAGE, ENDWAIT) \
  {                                                                              \
    bf16_t* ksb = (bf16_t*)(smem + (BUF) * 16384);                               \
    bf16_t* vsb = (bf16_t*)(smem + (BUF) * 16384 + 8192);                        \
    if (DOSTAGE) {                                                               \
      bf16_t* kn = (bf16_t*)(smem + (NBUF) * 16384);                             \
      const bf16_t* kbase = kb0 + (size_t)((KT) + 2) * 4096;                     \
      const bf16_t* vbase = vb0 + (size_t)((KT) + 2) * 64;                       \
      _Pragma("unroll")                                                          \
      for (int i = 0; i < 2; i++) {                                              \
        int g = t + i * 256;                                                     \
        int r = g >> 3, pc = g & 7;                                              \
        int lc = pc ^ (r & 7);                                                   \
        gl_lds16(kbase + (size_t)r * 64 + lc * 8, kn + i * 2048 + w * 512);      \
        gl_lds16(vbase + (size_t)r * 2048 + lc * 8, kn + 4096 + i * 2048 + w * 512); \
      }                                                                          \
    }                                                                            \
    SCHED_FENCE();                                                               \
    f32x4 sc[2][4];                                                              \
    _Pragma("unroll")                                                            \
    for (int gq = 0; gq < 2; gq++)                                               \
      _Pragma("unroll")                                                          \
      for (int j = 0; j < 4; j++) sc[gq][j] = zero;                              \
    __builtin_amdgcn_s_setprio(1);                                               \
    if (!(FIRST)) {                                                              \
      _Pragma("unroll")                                                          \
      for (int ks2 = 0; ks2 < 2; ks2++)                                          \
        _Pragma("unroll")                                                        \
        for (int et = 0; et < 4; et++) {                                         \
          O[0][et] = mfma16((VFIN)[ks2 * 4 + et], (PBIN)[0][ks2], O[0][et]);     \
          O[1][et] = mfma16((VFIN)[ks2 * 4 + et], (PBIN)[1][ks2], O[1][et]);     \
        }                                                                        \
    }                                                                            \
    _Pragma("unroll")                                                            \
    for (int kk = 0; kk < 2; kk++)                                               \
      _Pragma("unroll")                                                          \
      for (int j = 0; j < 4; j++) {                                              \
        int R = j * 16 + lr;                                                     \
        int ch = (kk * 4 + lq) ^ (R & 7);                                        \
        bf16x8 kf = *(const bf16x8*)(ksb + R * 64 + ch * 8);                     \
        sc[0][j] = mfma16(kf, qf[0][kk], sc[0][j]);                              \
        sc[1][j] = mfma16(kf, qf[1][kk], sc[1][j]);                              \
      }                                                                          \
    __builtin_amdgcn_s_setprio(0);                                               \
    _Pragma("unroll")                                                            \
    for (int ks2 = 0; ks2 < 2; ks2++)                                            \
      _Pragma("unroll")                                                          \
      for (int et = 0; et < 4; et++) {                                           \
        int R = et * 16 + lr;                                                    \
        int ch = (ks2 * 4 + lq) ^ (R & 7);                                       \
        (VFOUT)[ks2 * 4 + et] = *(const bf16x8*)(vsb + R * 64 + ch * 8);         \
      }                                                                          \
    _Pragma("unroll")                                                            \
    for (int gq = 0; gq < 2; gq++)                                               \
      _Pragma("unroll")                                                          \
      for (int ks2 = 0; ks2 < 2; ks2++)                                          \
        _Pragma("unroll")                                                        \
        for (int r = 0; r < 4; r++) {                                            \
          float e0 = exp2_fast(sc[gq][2 * ks2][r]);                              \
          float e1 = exp2_fast(sc[gq][2 * ks2 + 1][r]);                          \
          f32x2 ee = {e0, e1};                                                   \
          lsv[gq] += ee;                                                         \
          (PBOUT)[gq][ks2][r] = (bf16_t)e0;                                      \
          (PBOUT)[gq][ks2][4 + r] = (bf16_t)e1;                                  \
        }                                                                        \
    /* my reads of buf[BUF] done + my tile-(KT+1) loads retired; barrier */      \
    /* makes both all-waves guarantees before anyone touches those bufs. */      \
    asm volatile("s_waitcnt vmcnt(" ENDWAIT ") lgkmcnt(0)");                     \
    SCHED_FENCE();                                                               \
    RAW_BAR();                                                                   \
  }

  ATTN_BODY(0, 0, 2, pbA, pbB, vfA, vfB, true,  true, "4");
  ATTN_BODY(1, 1, 0, pbB, pbA, vfB, vfA, false, true, "4");
  ATTN_BODY(2, 2, 1, pbA, pbB, vfA, vfB, false, true, "4");
  ATTN_BODY(3, 0, 2, pbB, pbA, vfB, vfA, false, true, "4");
  ATTN_BODY(4, 1, 0, pbA, pbB, vfA, vfB, false, true, "4");
  ATTN_BODY(5, 2, 1, pbB, pbA, vfB, vfA, false, true, "4");
  for (int g6 = 6; g6 < 30; g6 += 6) {
    ATTN_BODY(g6 + 0, 0, 2, pbA, pbB, vfA, vfB, false, true, "4");
    ATTN_BODY(g6 + 1, 1, 0, pbB, pbA, vfB, vfA, false, true, "4");
    ATTN_BODY(g6 + 2, 2, 1, pbA, pbB, vfA, vfB, false, true, "4");
    ATTN_BODY(g6 + 3, 0, 2, pbB, pbA, vfB, vfA, false, true, "4");
    ATTN_BODY(g6 + 4, 1, 0, pbA, pbB, vfA, vfB, false, true, "4");
    ATTN_BODY(g6 + 5, 2, 1, pbB, pbA, vfB, vfA, false, true, "4");
  }
  ATTN_BODY(30, 0, 2, pbA, pbB, vfA, vfB, false, false, "0");
  ATTN_BODY(31, 1, 0, pbB, pbA, vfB, vfA, false, false, "0");
#undef ATTN_BODY

  // epilogue PV: tile 31 (pbB + vfB)
  #pragma unroll
  for (int ks2 = 0; ks2 < 2; ks2++)
    #pragma unroll
    for (int et = 0; et < 4; et++) {
      O[0][et] = mfma16(vfB[ks2 * 4 + et], pbB[0][ks2], O[0][et]);
      O[1][et] = mfma16(vfB[ks2 * 4 + et], pbB[1][ks2], O[1][et]);
    }

  float s0 = lsv[0][0] + lsv[0][1];
  float s1 = lsv[1][0] + lsv[1][1];
  s0 += __shfl_xor(s0, 16);
  s0 += __shfl_xor(s0, 32);
  s1 += __shfl_xor(s1, 16);
  s1 += __shfl_xor(s1, 32);
  float rinv[2] = {1.0f / s0, 1.0f / s1};

  // epilogue: LDS transpose (128 x 72 pitch = 18.4 KB at smem base; all buffer
  // reads drained by the final RAW_BAR) then coalesced store.
  bf16_t* ts = (bf16_t*)smem;
  #pragma unroll
  for (int gq = 0; gq < 2; gq++)
    #pragma unroll
    for (int et = 0; et < 4; et++) {
      bf16x4 pv;
      #pragma unroll
      for (int r = 0; r < 4; r++) pv[r] = (bf16_t)(O[gq][et][r] * rinv[gq]);
      *(bf16x4*)(ts + (w * 32 + gq * 16 + lr) * 72 + et * 16 + lq * 4) = pv;
    }
  __syncthreads();
  const int b = bh >> 4, h = bh & 15;
  #pragma unroll
  for (int i = 0; i < 4; i++) {
    int c = t + i * 256;
    int row = c >> 3, c8 = c & 7;
    bf16x8 vv = *(const bf16x8*)(ts + row * 72 + c8 * 8);
    *(bf16x8*)(att + ((size_t)b * 2048 + qt * 128 + row) * 1024 + h * 64 + c8 * 8) = vv;
  }
}

// ---------------- output projection (A bf16, W bf16, out fp32) ----------------
__global__ __launch_bounds__(256, 3) void gemm_out(
    const bf16_t* __restrict__ A, const bf16_t* __restrict__ W,
    const float* __restrict__ bias, float* __restrict__ out)
{
  __shared__ __attribute__((aligned(16))) unsigned char smem[49152];
  const bf16_t* Ab = A + (size_t)blockIdx.x * 64 * 1024;
  const bf16_t* Wb = W + (size_t)blockIdx.y * 128 * 1024;
  const int t = threadIdx.x, w = t >> 6, l = t & 63, lq = l >> 4, lr = l & 15;
  const int mh = w & 1, nh = w >> 1;

  f32x4 acc[2][4];
  f32x4 zero = {0.f, 0.f, 0.f, 0.f};
  #pragma unroll
  for (int i = 0; i < 2; i++)
    #pragma unroll
    for (int j = 0; j < 4; j++) acc[i][j] = zero;

  stage64(Ab, (bf16_t*)smem, t, w);
  stage128(Wb, (bf16_t*)(smem + 8192), t, w);
  WAIT_VM0();
  RAW_BAR();

  for (int step = 0; step < 16; ++step) {
    const int cur = step & 1;
    bf16_t* as = (bf16_t*)(smem + cur * 24576);
    bf16_t* bs = (bf16_t*)(smem + cur * 24576 + 8192);
    if (step < 15) {
      bf16_t* an = (bf16_t*)(smem + (cur ^ 1) * 24576);
      stage64(Ab + (step + 1) * 64, an, t, w);
      stage128(Wb + (step + 1) * 64, an + 4096, t, w);
    }
    SCHED_FENCE();
    #pragma unroll
    for (int kk = 0; kk < 2; kk++) {
      bf16x8 af[2], bfr[4];
      #pragma unroll
      for (int i = 0; i < 2; i++) {
        int R = mh * 32 + i * 16 + lr;
        int ch = (kk * 4 + lq) ^ (R & 7);
        af[i] = *(const bf16x8*)(as + R * 64 + ch * 8);
      }
      #pragma unroll
      for (int j = 0; j < 4; j++) {
        int R = nh * 64 + j * 16 + lr;
        int ch = (kk * 4 + lq) ^ (R & 7);
        bfr[j] = *(const bf16x8*)(bs + R * 64 + ch * 8);
      }
      __builtin_amdgcn_s_setprio(1);
      #pragma unroll
      for (int i = 0; i < 2; i++)
        #pragma unroll
        for (int j = 0; j < 4; j++)
          acc[i][j] = mfma16(af[i], bfr[j], acc[i][j]);
      __builtin_amdgcn_s_setprio(0);
    }
    WAIT_VM0();
    RAW_BAR();
  }

  #pragma unroll
  for (int i = 0; i < 2; i++) {
    #pragma unroll
    for (int j = 0; j < 4; j++) {
      int col = blockIdx.y * 128 + nh * 64 + j * 16 + lr;
      float bz = bias[col];
      #pragma unroll
      for (int r = 0; r < 4; r++) {
        int row = blockIdx.x * 64 + mh * 32 + i * 16 + lq * 4 + r;
        out[(size_t)row * 1024 + col] = acc[i][j][r] + bz;
      }
    }
  }
}

// ---------------- launch ----------------
extern "C" void kernel_launch(void* const* d_in, const int* in_sizes, int n_in,
                              void* d_out, int out_size, void* d_ws, size_t ws_size,
                              hipStream_t stream) {
  (void)in_sizes; (void)n_in; (void)out_size;
  const float* V  = (const float*)d_in[0];
  const float* Kx = (const float*)d_in[1];
  const float* Q  = (const float*)d_in[2];
  const float* Wv = (const float*)d_in[3];
  const float* bv = (const float*)d_in[4];
  const float* Wk = (const float*)d_in[5];
  const float* bk = (const float*)d_in[6];
  const float* Wq = (const float*)d_in[7];
  const float* bq = (const float*)d_in[8];
  const float* Wo = (const float*)d_in[9];
  const float* bo = (const float*)d_in[10];

  const size_t E = 1048576;
  if (ws_size < 20 * E * sizeof(bf16_t)) return;  // 40 MB needed

  bf16_t* ws = (bf16_t*)d_ws;
  bf16_t* cWo   = ws;            // 1E
  bf16_t* cWv   = ws + E;        // 1E
  bf16_t* cWk   = ws + 2 * E;    // 1E
  bf16_t* cWq   = ws + 3 * E;    // 1E
  bf16_t* q_ws  = ws + 4 * E;    // 4E  [bh][s][e], pre-scaled by 0.125*log2(e)
  bf16_t* k_ws  = ws + 8 * E;    // 4E  [bh][s][e]
  bf16_t* vt_ws = ws + 12 * E;   // 4E  [bh][e][s_perm]
  bf16_t* att_ws= ws + 16 * E;   // 4E  [b][s][h*64+e]

  bf16_t* cV = att_ws;                         // 8 MB (dead until attn)
  bf16_t* cK = (bf16_t*)d_out;                 // 8 MB (dead until gemm_out)
  bf16_t* cQ = (bf16_t*)d_out + 4 * E;         // 8 MB

  CvtArgs ca;
  ca.src[0] = Wo; ca.src[1] = Wv; ca.src[2] = Wk; ca.src[3] = Wq;
  ca.src[4] = V;  ca.src[5] = Kx; ca.src[6] = Q;
  ca.dst[0] = cWo; ca.dst[1] = cWv; ca.dst[2] = cWk; ca.dst[3] = cWq;
  ca.dst[4] = cV;  ca.dst[5] = cK;  ca.dst[6] = cQ;
  convert_all<<<8192, 256, 0, stream>>>(ca);

  ProjArgs pa;
  pa.A[0] = cV;  pa.A[1] = cK;  pa.A[2] = cQ;
  pa.W[0] = cWv; pa.W[1] = cWk; pa.W[2] = cWq;
  pa.bias[0] = bv; pa.bias[1] = bk; pa.bias[2] = bq;
  pa.out[0] = vt_ws; pa.out[1] = k_ws; pa.out[2] = q_ws;
  // Q pre-scale folds softmax's log2(e): exp(s/8) == 2^(s * 0.125 * log2e)
  pa.scale[0] = 1.f; pa.scale[1] = 1.f; pa.scale[2] = 0.125f * 1.4426950408889634f;
  gemm_proj<<<dim3(32, 8, 3), 256, 0, stream>>>(pa);

  attn<<<dim3(32, 16), 256, 0, stream>>>(q_ws, k_ws, vt_ws, att_ws);

  gemm_out<<<dim3(64, 8), 256, 0, stream>>>(att_ws, cWo, bo, (float*)d_out);
}

// Round 6
// 200.286 us; speedup vs baseline: 1.0784x; 1.0221x over previous
//
#include <hip/hip_runtime.h>
#include <cstdint>
#include <cstddef>

typedef __bf16 bf16_t;
typedef bf16_t bf16x8 __attribute__((ext_vector_type(8)));
typedef bf16_t bf16x4 __attribute__((ext_vector_type(4)));
typedef float f32x4 __attribute__((ext_vector_type(4)));
typedef float f32x2 __attribute__((ext_vector_type(2)));

__device__ __forceinline__ void gl_lds16(const void* g, void* l) {
  __builtin_amdgcn_global_load_lds(
      (const __attribute__((address_space(1))) void*)g,
      (__attribute__((address_space(3))) void*)l, 16, 0, 0);
}

__device__ __forceinline__ f32x4 mfma16(bf16x8 a, bf16x8 b, f32x4 c) {
  return __builtin_amdgcn_mfma_f32_16x16x32_bf16(a, b, c, 0, 0, 0);
}

// 2^x in one TRANS op (log2e is pre-folded into the Q scale).
__device__ __forceinline__ float exp2_fast(float x) {
  float r;
  asm("v_exp_f32 %0, %1" : "=v"(r) : "v"(x));
  return r;
}

// Scheduling fences: rule #18 — pin inline-asm waitcnts and raw barriers.
#define SCHED_FENCE() __builtin_amdgcn_sched_barrier(0)
#define WAIT_VM0()   do { asm volatile("s_waitcnt vmcnt(0)");   SCHED_FENCE(); } while (0)
#define WAIT_LGKM0() do { asm volatile("s_waitcnt lgkmcnt(0)"); SCHED_FENCE(); } while (0)
#define RAW_BAR()    do { __builtin_amdgcn_s_barrier();         SCHED_FENCE(); } while (0)

// ---------------- fp32 -> bf16 convert: 4 weights (1M elems) + 3 activations (4M) ---
struct CvtArgs { const float* src[7]; bf16_t* dst[7]; };

__global__ __launch_bounds__(256) void convert_all(CvtArgs a) {
  unsigned g = blockIdx.x * 256u + threadIdx.x;   // 2,097,152 groups of 8
  unsigned seg, off;
  if (g < 524288u) {            // weights: 4 x 131072 groups
    seg = g >> 17; off = g & 131071u;
  } else {                      // activations: 3 x 524288 groups
    unsigned h = g - 524288u;
    seg = 4u + (h >> 19); off = h & 524287u;
  }
  const float4* s = (const float4*)a.src[seg] + (size_t)off * 2;
  float4 x0 = s[0], x1 = s[1];
  bf16x8 o;
  o[0] = (bf16_t)x0.x; o[1] = (bf16_t)x0.y; o[2] = (bf16_t)x0.z; o[3] = (bf16_t)x0.w;
  o[4] = (bf16_t)x1.x; o[5] = (bf16_t)x1.y; o[6] = (bf16_t)x1.z; o[7] = (bf16_t)x1.w;
  *(bf16x8*)(a.dst[seg] + (size_t)off * 8) = o;
}

// ---------------- staging helpers (pre-swizzled global source, linear LDS dest) ----
__device__ __forceinline__ void stage128(const bf16_t* src, bf16_t* dst, int t, int w) {
  #pragma unroll
  for (int i = 0; i < 4; i++) {
    int g = t + i * 256;
    int r = g >> 3, pc = g & 7;
    int lc = pc ^ (r & 7);
    gl_lds16(src + (size_t)r * 1024 + lc * 8, dst + i * 2048 + w * 512);
  }
}
__device__ __forceinline__ void stage64(const bf16_t* src, bf16_t* dst, int t, int w) {
  #pragma unroll
  for (int i = 0; i < 2; i++) {
    int g = t + i * 256;
    int r = g >> 3, pc = g & 7;
    int lc = pc ^ (r & 7);
    gl_lds16(src + (size_t)r * 1024 + lc * 8, dst + i * 2048 + w * 512);
  }
}

// ---------------- fused QKV projection (A bf16, W bf16, out bf16) ----------------
// z=0: V -> vt [bh][e][s_perm]; z=1: K -> [bh][s][e]; z=2: Q -> [bh][s][e]*qscale
struct ProjArgs {
  const bf16_t* A[3]; const bf16_t* W[3]; const float* bias[3];
  bf16_t* out[3]; float scale[3];
};

__global__ __launch_bounds__(256, 2) void gemm_proj(ProjArgs p) {
  __shared__ __attribute__((aligned(16))) unsigned char smem[65536];
  const int z = blockIdx.z;
  const bf16_t* A = p.A[z] + (size_t)blockIdx.x * 128 * 1024;
  const bf16_t* W = p.W[z] + (size_t)blockIdx.y * 128 * 1024;

  const int t = threadIdx.x;
  const int w = t >> 6, l = t & 63;
  const int lq = l >> 4, lr = l & 15;
  const int mq = w & 1, nq = w >> 1;

  f32x4 acc[4][4];
  f32x4 zero = {0.f, 0.f, 0.f, 0.f};
  #pragma unroll
  for (int i = 0; i < 4; i++)
    #pragma unroll
    for (int j = 0; j < 4; j++) acc[i][j] = zero;

  stage128(A, (bf16_t*)smem, t, w);
  stage128(W, (bf16_t*)(smem + 16384), t, w);
  WAIT_VM0();
  RAW_BAR();

  for (int step = 0; step < 16; ++step) {
    const int cur = step & 1;
    bf16_t* as = (bf16_t*)(smem + cur * 32768);
    bf16_t* bs = (bf16_t*)(smem + cur * 32768 + 16384);
    if (step < 15) {
      bf16_t* an = (bf16_t*)(smem + (cur ^ 1) * 32768);
      stage128(A + (step + 1) * 64, an, t, w);
      stage128(W + (step + 1) * 64, an + 8192, t, w);
    }
    SCHED_FENCE();
    #pragma unroll
    for (int kk = 0; kk < 2; kk++) {
      bf16x8 af[4], bfr[4];
      #pragma unroll
      for (int i = 0; i < 4; i++) {
        int R = mq * 64 + i * 16 + lr;
        int ch = (kk * 4 + lq) ^ (R & 7);
        af[i] = *(const bf16x8*)(as + R * 64 + ch * 8);
      }
      #pragma unroll
      for (int j = 0; j < 4; j++) {
        int R = nq * 64 + j * 16 + lr;
        int ch = (kk * 4 + lq) ^ (R & 7);
        bfr[j] = *(const bf16x8*)(bs + R * 64 + ch * 8);
      }
      __builtin_amdgcn_s_setprio(1);
      #pragma unroll
      for (int i = 0; i < 4; i++)
        #pragma unroll
        for (int j = 0; j < 4; j++)
          acc[i][j] = mfma16(af[i], bfr[j], acc[i][j]);
      __builtin_amdgcn_s_setprio(0);
    }
    WAIT_VM0();
    RAW_BAR();
  }

  const float* bias = p.bias[z];
  const float scale = p.scale[z];
  __syncthreads();
  bf16_t* ts = (bf16_t*)smem;  // 128 x 136 bf16 = 34,816 B
  #pragma unroll
  for (int i = 0; i < 4; i++) {
    #pragma unroll
    for (int j = 0; j < 4; j++) {
      int nl = nq * 64 + j * 16 + lr;
      float bz = bias[blockIdx.y * 128 + nl];
      #pragma unroll
      for (int r = 0; r < 4; r++) {
        int ml = mq * 64 + i * 16 + lq * 4 + r;
        bf16_t val = (bf16_t)((acc[i][j][r] + bz) * scale);
        if (z == 0) {
          int mlp = (ml & 96) | (((ml >> 2) & 3) << 3) | (((ml >> 4) & 1) << 2) | (ml & 3);
          ts[nl * 136 + mlp] = val;   // transposed (+permuted) for vt
        } else {
          ts[ml * 136 + nl] = val;
        }
      }
    }
  }
  __syncthreads();
  bf16_t* out = p.out[z];
  const int b = blockIdx.x >> 4, sbase = (blockIdx.x & 15) * 128;
  if (z == 0) {
    #pragma unroll
    for (int ii = 0; ii < 8; ii++) {
      int idx = t * 8 + ii * 2048;
      int rr = idx >> 7, cc = idx & 127;
      int n = blockIdx.y * 128 + rr;
      int h = n >> 6, e = n & 63;
      bf16x8 vq = *(const bf16x8*)(ts + rr * 136 + cc);
      *(bf16x8*)(out + ((size_t)(b * 16 + h) * 64 + e) * 2048 + sbase + cc) = vq;
    }
  } else {
    #pragma unroll
    for (int ii = 0; ii < 8; ii++) {
      int idx = t * 8 + ii * 2048;
      int rr = idx >> 7, cc = idx & 127;
      int n = blockIdx.y * 128 + cc;
      int h = n >> 6, e = n & 63;
      bf16x8 vq = *(const bf16x8*)(ts + rr * 136 + cc);
      *(bf16x8*)(out + ((size_t)(b * 16 + h) * 2048 + sbase + rr) * 64 + e) = vq;
    }
  }
}

// ---------------- flash attention, S^T formulation -----------------------------
// R6: KVBLK=128 — 16 iterations instead of 32. R2/R3/R5 showed a ~3000-cycle
// per-iteration wall INVARIANT to pipeline depth and per-wave work: the cost is
// per-tile fixed overhead (barrier + drains + non-overlapped softmax burst).
// Halving tile count halves that. The 2x longer compute phase now covers staging
// latency, so the simple race-free 2-phase handshake (stage at top, vmcnt(0)+
// lgkmcnt(0)+barrier at bottom — gemm_proj's proven pattern) replaces the R5
// 3-buffer rotation. Softmax and PV interleave per 32-key chunk (exp of chunk
// i+1 overlaps PV MFMAs of chunk i on separate pipes). LDS 64KB = 2 x 32KB
// buffers; Q stages through buf1 pre-loop. sc[2][8]=64 VGPR; pb/vf transient.
__global__ __launch_bounds__(256, 2) void attn(
    const bf16_t* __restrict__ qw, const bf16_t* __restrict__ kw,
    const bf16_t* __restrict__ vtw, bf16_t* __restrict__ att)
{
  __shared__ __attribute__((aligned(16))) unsigned char smem[65536];
  // buf_c = smem + c*32K = [K 128x64 16KB | V 64x128 16KB]
  const int bh = blockIdx.x, qt = blockIdx.y;
  const int t = threadIdx.x, w = t >> 6, l = t & 63, lq = l >> 4, lr = l & 15;

  const bf16_t* kb0 = kw + (size_t)bh * 131072;
  const bf16_t* vb0 = vtw + (size_t)bh * 131072;
  bf16_t* qstage = (bf16_t*)(smem + 32768);   // buf1 K-region (16KB)

  // prologue: Q -> buf1.K (4 loads), K0/V0 -> buf0 (8 loads)
  const bf16_t* qbase = qw + ((size_t)bh * 2048 + qt * 128) * 64;
  #pragma unroll
  for (int i = 0; i < 4; i++) {
    int g = t + i * 256;
    int r = g >> 3, pc = g & 7;
    int lc = pc ^ (r & 7);
    gl_lds16(qbase + (size_t)r * 64 + lc * 8, qstage + i * 2048 + w * 512);
  }
  #pragma unroll
  for (int i = 0; i < 4; i++) {      // K0: 128 rows x 64, row stride 64
    int g = t + i * 256;
    int r = g >> 3, pc = g & 7;
    int lc = pc ^ (r & 7);
    gl_lds16(kb0 + (size_t)r * 64 + lc * 8, (bf16_t*)smem + i * 2048 + w * 512);
  }
  #pragma unroll
  for (int i = 0; i < 4; i++) {      // V0: 64 rows x 128, row stride 2048
    int g = t + i * 256;
    int r = g >> 4, c16 = g & 15;
    int lc = c16 ^ (r & 7);
    gl_lds16(vb0 + (size_t)r * 2048 + lc * 8, (bf16_t*)(smem + 16384) + i * 2048 + w * 512);
  }
  asm volatile("s_waitcnt vmcnt(8)");  // my Q loads retired; bar -> all Q landed
  SCHED_FENCE();
  RAW_BAR();
  bf16x8 qf[2][2];
  #pragma unroll
  for (int gq = 0; gq < 2; gq++)
    #pragma unroll
    for (int kk = 0; kk < 2; kk++) {
      int R = w * 32 + gq * 16 + lr;
      int ch = (kk * 4 + lq) ^ (R & 7);
      qf[gq][kk] = *(const bf16x8*)(qstage + R * 64 + ch * 8);
    }
  // my K0/V0 retired + my Q ds_reads done; bar -> tile 0 landed for all waves
  // and buf1 (Q region) is free for staging.
  asm volatile("s_waitcnt vmcnt(0) lgkmcnt(0)");
  SCHED_FENCE();
  RAW_BAR();

  f32x4 O[2][4];
  f32x4 zero = {0.f, 0.f, 0.f, 0.f};
  #pragma unroll
  for (int gq = 0; gq < 2; gq++)
    #pragma unroll
    for (int et = 0; et < 4; et++) O[gq][et] = zero;
  f32x2 lsv[2];
  lsv[0] = f32x2{0.f, 0.f}; lsv[1] = f32x2{0.f, 0.f};

  for (int kt = 0; kt < 16; ++kt) {
    const int cur = kt & 1;
    bf16_t* ksb = (bf16_t*)(smem + cur * 32768);
    bf16_t* vsb = (bf16_t*)(smem + cur * 32768 + 16384);
    if (kt < 15) {
      bf16_t* kn = (bf16_t*)(smem + (cur ^ 1) * 32768);
      const bf16_t* kbase = kb0 + (size_t)(kt + 1) * 8192;
      const bf16_t* vbase = vb0 + (size_t)(kt + 1) * 128;
      #pragma unroll
      for (int i = 0; i < 4; i++) {
        int g = t + i * 256;
        int r = g >> 3, pc = g & 7;
        int lc = pc ^ (r & 7);
        gl_lds16(kbase + (size_t)r * 64 + lc * 8, kn + i * 2048 + w * 512);
      }
      #pragma unroll
      for (int i = 0; i < 4; i++) {
        int g = t + i * 256;
        int r = g >> 4, c16 = g & 15;
        int lc = c16 ^ (r & 7);
        gl_lds16(vbase + (size_t)r * 2048 + lc * 8, kn + 8192 + i * 2048 + w * 512);
      }
    }
    SCHED_FENCE();

    // QK^T: 128 keys -> sc[gq][j], j = key/16
    f32x4 sc[2][8];
    #pragma unroll
    for (int gq = 0; gq < 2; gq++)
      #pragma unroll
      for (int j = 0; j < 8; j++) sc[gq][j] = zero;
    __builtin_amdgcn_s_setprio(1);
    #pragma unroll
    for (int kk = 0; kk < 2; kk++)
      #pragma unroll
      for (int j = 0; j < 8; j++) {
        int R = j * 16 + lr;
        int ch = (kk * 4 + lq) ^ (R & 7);
        bf16x8 kf = *(const bf16x8*)(ksb + R * 64 + ch * 8);
        sc[0][j] = mfma16(kf, qf[0][kk], sc[0][j]);
        sc[1][j] = mfma16(kf, qf[1][kk], sc[1][j]);
      }
    __builtin_amdgcn_s_setprio(0);

    // softmax + PV interleaved per 32-key chunk (ks2 = 0..3)
    #pragma unroll
    for (int ks2 = 0; ks2 < 4; ks2++) {
      bf16x8 pb0, pb1;
      #pragma unroll
      for (int r = 0; r < 4; r++) {
        float e00 = exp2_fast(sc[0][2 * ks2][r]);
        float e01 = exp2_fast(sc[0][2 * ks2 + 1][r]);
        float e10 = exp2_fast(sc[1][2 * ks2][r]);
        float e11 = exp2_fast(sc[1][2 * ks2 + 1][r]);
        f32x2 ee0 = {e00, e01}, ee1 = {e10, e11};
        lsv[0] += ee0; lsv[1] += ee1;
        pb0[r] = (bf16_t)e00; pb0[4 + r] = (bf16_t)e01;
        pb1[r] = (bf16_t)e10; pb1[4 + r] = (bf16_t)e11;
      }
      bf16x8 vf[4];
      #pragma unroll
      for (int et = 0; et < 4; et++) {
        int R = et * 16 + lr;
        int cc = ks2 * 4 + lq;
        int ph = cc ^ (R & 7);
        vf[et] = *(const bf16x8*)(vsb + R * 128 + ph * 8);
      }
      __builtin_amdgcn_s_setprio(1);
      #pragma unroll
      for (int et = 0; et < 4; et++) {
        O[0][et] = mfma16(vf[et], pb0, O[0][et]);
        O[1][et] = mfma16(vf[et], pb1, O[1][et]);
      }
      __builtin_amdgcn_s_setprio(0);
    }

    // my reads of buf[cur] done + my tile-(kt+1) loads retired; barrier makes
    // both all-waves guarantees before anyone touches those buffers.
    asm volatile("s_waitcnt vmcnt(0) lgkmcnt(0)");
    SCHED_FENCE();
    RAW_BAR();
  }

  float s0 = lsv[0][0] + lsv[0][1];
  float s1 = lsv[1][0] + lsv[1][1];
  s0 += __shfl_xor(s0, 16);
  s0 += __shfl_xor(s0, 32);
  s1 += __shfl_xor(s1, 16);
  s1 += __shfl_xor(s1, 32);
  float rinv[2] = {1.0f / s0, 1.0f / s1};

  // epilogue: LDS transpose (128 x 72 pitch = 18.4 KB at smem base; all buffer
  // reads drained by the final RAW_BAR) then coalesced store.
  bf16_t* ts = (bf16_t*)smem;
  #pragma unroll
  for (int gq = 0; gq < 2; gq++)
    #pragma unroll
    for (int et = 0; et < 4; et++) {
      bf16x4 pv;
      #pragma unroll
      for (int r = 0; r < 4; r++) pv[r] = (bf16_t)(O[gq][et][r] * rinv[gq]);
      *(bf16x4*)(ts + (w * 32 + gq * 16 + lr) * 72 + et * 16 + lq * 4) = pv;
    }
  __syncthreads();
  const int b = bh >> 4, h = bh & 15;
  #pragma unroll
  for (int i = 0; i < 4; i++) {
    int c = t + i * 256;
    int row = c >> 3, c8 = c & 7;
    bf16x8 vv = *(const bf16x8*)(ts + row * 72 + c8 * 8);
    *(bf16x8*)(att + ((size_t)b * 2048 + qt * 128 + row) * 1024 + h * 64 + c8 * 8) = vv;
  }
}

// ---------------- output projection (A bf16, W bf16, out fp32) ----------------
__global__ __launch_bounds__(256, 3) void gemm_out(
    const bf16_t* __restrict__ A, const bf16_t* __restrict__ W,
    const float* __restrict__ bias, float* __restrict__ out)
{
  __shared__ __attribute__((aligned(16))) unsigned char smem[49152];
  const bf16_t* Ab = A + (size_t)blockIdx.x * 64 * 1024;
  const bf16_t* Wb = W + (size_t)blockIdx.y * 128 * 1024;
  const int t = threadIdx.x, w = t >> 6, l = t & 63, lq = l >> 4, lr = l & 15;
  const int mh = w & 1, nh = w >> 1;

  f32x4 acc[2][4];
  f32x4 zero = {0.f, 0.f, 0.f, 0.f};
  #pragma unroll
  for (int i = 0; i < 2; i++)
    #pragma unroll
    for (int j = 0; j < 4; j++) acc[i][j] = zero;

  stage64(Ab, (bf16_t*)smem, t, w);
  stage128(Wb, (bf16_t*)(smem + 8192), t, w);
  WAIT_VM0();
  RAW_BAR();

  for (int step = 0; step < 16; ++step) {
    const int cur = step & 1;
    bf16_t* as = (bf16_t*)(smem + cur * 24576);
    bf16_t* bs = (bf16_t*)(smem + cur * 24576 + 8192);
    if (step < 15) {
      bf16_t* an = (bf16_t*)(smem + (cur ^ 1) * 24576);
      stage64(Ab + (step + 1) * 64, an, t, w);
      stage128(Wb + (step + 1) * 64, an + 4096, t, w);
    }
    SCHED_FENCE();
    #pragma unroll
    for (int kk = 0; kk < 2; kk++) {
      bf16x8 af[2], bfr[4];
      #pragma unroll
      for (int i = 0; i < 2; i++) {
        int R = mh * 32 + i * 16 + lr;
        int ch = (kk * 4 + lq) ^ (R & 7);
        af[i] = *(const bf16x8*)(as + R * 64 + ch * 8);
      }
      #pragma unroll
      for (int j = 0; j < 4; j++) {
        int R = nh * 64 + j * 16 + lr;
        int ch = (kk * 4 + lq) ^ (R & 7);
        bfr[j] = *(const bf16x8*)(bs + R * 64 + ch * 8);
      }
      __builtin_amdgcn_s_setprio(1);
      #pragma unroll
      for (int i = 0; i < 2; i++)
        #pragma unroll
        for (int j = 0; j < 4; j++)
          acc[i][j] = mfma16(af[i], bfr[j], acc[i][j]);
      __builtin_amdgcn_s_setprio(0);
    }
    WAIT_VM0();
    RAW_BAR();
  }

  #pragma unroll
  for (int i = 0; i < 2; i++) {
    #pragma unroll
    for (int j = 0; j < 4; j++) {
      int col = blockIdx.y * 128 + nh * 64 + j * 16 + lr;
      float bz = bias[col];
      #pragma unroll
      for (int r = 0; r < 4; r++) {
        int row = blockIdx.x * 64 + mh * 32 + i * 16 + lq * 4 + r;
        out[(size_t)row * 1024 + col] = acc[i][j][r] + bz;
      }
    }
  }
}

// ---------------- launch ----------------
extern "C" void kernel_launch(void* const* d_in, const int* in_sizes, int n_in,
                              void* d_out, int out_size, void* d_ws, size_t ws_size,
                              hipStream_t stream) {
  (void)in_sizes; (void)n_in; (void)out_size;
  const float* V  = (const float*)d_in[0];
  const float* Kx = (const float*)d_in[1];
  const float* Q  = (const float*)d_in[2];
  const float* Wv = (const float*)d_in[3];
  const float* bv = (const float*)d_in[4];
  const float* Wk = (const float*)d_in[5];
  const float* bk = (const float*)d_in[6];
  const float* Wq = (const float*)d_in[7];
  const float* bq = (const float*)d_in[8];
  const float* Wo = (const float*)d_in[9];
  const float* bo = (const float*)d_in[10];

  const size_t E = 1048576;
  if (ws_size < 20 * E * sizeof(bf16_t)) return;  // 40 MB needed

  bf16_t* ws = (bf16_t*)d_ws;
  bf16_t* cWo   = ws;            // 1E
  bf16_t* cWv   = ws + E;        // 1E
  bf16_t* cWk   = ws + 2 * E;    // 1E
  bf16_t* cWq   = ws + 3 * E;    // 1E
  bf16_t* q_ws  = ws + 4 * E;    // 4E  [bh][s][e], pre-scaled by 0.125*log2(e)
  bf16_t* k_ws  = ws + 8 * E;    // 4E  [bh][s][e]
  bf16_t* vt_ws = ws + 12 * E;   // 4E  [bh][e][s_perm]
  bf16_t* att_ws= ws + 16 * E;   // 4E  [b][s][h*64+e]

  bf16_t* cV = att_ws;                         // 8 MB (dead until attn)
  bf16_t* cK = (bf16_t*)d_out;                 // 8 MB (dead until gemm_out)
  bf16_t* cQ = (bf16_t*)d_out + 4 * E;         // 8 MB

  CvtArgs ca;
  ca.src[0] = Wo; ca.src[1] = Wv; ca.src[2] = Wk; ca.src[3] = Wq;
  ca.src[4] = V;  ca.src[5] = Kx; ca.src[6] = Q;
  ca.dst[0] = cWo; ca.dst[1] = cWv; ca.dst[2] = cWk; ca.dst[3] = cWq;
  ca.dst[4] = cV;  ca.dst[5] = cK;  ca.dst[6] = cQ;
  convert_all<<<8192, 256, 0, stream>>>(ca);

  ProjArgs pa;
  pa.A[0] = cV;  pa.A[1] = cK;  pa.A[2] = cQ;
  pa.W[0] = cWv; pa.W[1] = cWk; pa.W[2] = cWq;
  pa.bias[0] = bv; pa.bias[1] = bk; pa.bias[2] = bq;
  pa.out[0] = vt_ws; pa.out[1] = k_ws; pa.out[2] = q_ws;
  // Q pre-scale folds softmax's log2(e): exp(s/8) == 2^(s * 0.125 * log2e)
  pa.scale[0] = 1.f; pa.scale[1] = 1.f; pa.scale[2] = 0.125f * 1.4426950408889634f;
  gemm_proj<<<dim3(32, 8, 3), 256, 0, stream>>>(pa);

  attn<<<dim3(32, 16), 256, 0, stream>>>(q_ws, k_ws, vt_ws, att_ws);

  gemm_out<<<dim3(64, 8), 256, 0, stream>>>(att_ws, cWo, bo, (float*)d_out);
}